// Round 1
// baseline (4441.676 us; speedup 1.0000x reference)
//
#include <hip/hip_runtime.h>
#include <hip/hip_bf16.h>

#define Bq 4
#define Cc 128
#define Ff 64
#define Tt 2048
#define CF 8192     // C*F
#define NCHUNK 32   // cf chunks for QK pass
#define CHUNK 256   // cf per chunk

// ---------------------------------------------------------------------------
// K1: effective QK weights  Weff[cf][d] (d<10: q, d>=10: k), cf = c*64+f
// ---------------------------------------------------------------------------
__global__ void k_weff(const float* __restrict__ Wq_lin, const float* __restrict__ Wq_conv,
                       const float* __restrict__ Wk_lin, const float* __restrict__ Wk_conv,
                       float* __restrict__ weff) {
    int gid = blockIdx.x * 256 + threadIdx.x;
    if (gid >= CF * 20) return;
    int cf = gid / 20, d = gid % 20;
    int c = cf >> 6, f = cf & 63;
    float s = 0.f;
    if (d < 10) {
        #pragma unroll
        for (int o = 0; o < 4; ++o) s += Wq_lin[d * 256 + o * 64 + f] * Wq_conv[o * 128 + c];
    } else {
        int dd = d - 10;
        #pragma unroll
        for (int o = 0; o < 4; ++o) s += Wk_lin[dd * 256 + o * 64 + f] * Wk_conv[o * 128 + c];
    }
    weff[cf * 20 + d] = s;
}

// K1b: constants  cqk[d] = b_lin[d] + sum_{o,f} W_lin[d][o*64+f] * b_conv[o]
__global__ void k_const(const float* __restrict__ Wq_lin, const float* __restrict__ bq_conv,
                        const float* __restrict__ bq_lin, const float* __restrict__ Wk_lin,
                        const float* __restrict__ bk_conv, const float* __restrict__ bk_lin,
                        float* __restrict__ cqk) {
    int d = threadIdx.x;
    if (d >= 20) return;
    float s;
    if (d < 10) {
        s = bq_lin[d];
        for (int o = 0; o < 4; ++o) {
            float bb = bq_conv[o];
            for (int f = 0; f < 64; ++f) s += Wq_lin[d * 256 + o * 64 + f] * bb;
        }
    } else {
        int dd = d - 10;
        s = bk_lin[dd];
        for (int o = 0; o < 4; ++o) {
            float bb = bk_conv[o];
            for (int f = 0; f < 64; ++f) s += Wk_lin[dd * 256 + o * 64 + f] * bb;
        }
    }
    cqk[d] = s;
}

// ---------------------------------------------------------------------------
// K2: QK partials.  partial[b][ch][d][t] = sum_{cf in chunk} x[b][cf][t]*Weff[cf][d]
// grid: 4b * 32ch * 4tt = 512 blocks, 256 thr, 2 t per thread (float2 loads)
// ---------------------------------------------------------------------------
__global__ __launch_bounds__(256) void k_qk(const float* __restrict__ x,
                                            const float* __restrict__ weff,
                                            float* __restrict__ partial) {
    int blk = blockIdx.x;
    int tt = blk & 3;
    int ch = (blk >> 2) & 31;
    int b  = blk >> 7;
    int t = tt * 512 + threadIdx.x * 2;
    const float* xb = x + (size_t)b * CF * Tt;
    float acc[20][2];
    #pragma unroll
    for (int d = 0; d < 20; ++d) { acc[d][0] = 0.f; acc[d][1] = 0.f; }
    int cf0 = ch * CHUNK;
    for (int cf = cf0; cf < cf0 + CHUNK; ++cf) {
        float2 xv = *(const float2*)(xb + (size_t)cf * Tt + t);
        const float* w = weff + cf * 20;   // uniform address -> s_loads
        #pragma unroll
        for (int d = 0; d < 20; ++d) {
            float wv = w[d];
            acc[d][0] += wv * xv.x;
            acc[d][1] += wv * xv.y;
        }
    }
    float* pb = partial + (size_t)(b * NCHUNK + ch) * 20 * Tt;
    #pragma unroll
    for (int d = 0; d < 20; ++d)
        *(float2*)(pb + (size_t)d * Tt + t) = make_float2(acc[d][0], acc[d][1]);
}

// K3: reduce partials + const -> Q[b][t][10], Kt[b][10][t].  grid 32 x 256
__global__ void k_qkred(const float* __restrict__ partial, const float* __restrict__ cqk,
                        float* __restrict__ Q, float* __restrict__ Kt) {
    int t = blockIdx.x * 256 + threadIdx.x;  // 0..8191
    int b = t >> 11, tl = t & 2047;
    for (int d = 0; d < 20; ++d) {
        float s = cqk[d];
        for (int ch = 0; ch < NCHUNK; ++ch)
            s += partial[((size_t)(b * NCHUNK + ch) * 20 + d) * Tt + tl];
        if (d < 10) Q[(size_t)(b * 2048 + tl) * 10 + d] = s;
        else        Kt[((size_t)b * 10 + (d - 10)) * Tt + tl] = s;
    }
}

// ---------------------------------------------------------------------------
// K4: energy + softmax -> A[b][i][j].  block per (b,i): 8192 blocks x 256
// ---------------------------------------------------------------------------
__global__ __launch_bounds__(256) void k_att(const float* __restrict__ Q,
                                             const float* __restrict__ Kt,
                                             float* __restrict__ A) {
    int bi = blockIdx.x;
    int b = bi >> 11;
    __shared__ float qs[10];
    __shared__ float red[256];
    int tid = threadIdx.x;
    if (tid < 10) qs[tid] = Q[(size_t)bi * 10 + tid];
    __syncthreads();
    const float* kb = Kt + (size_t)b * 10 * Tt;
    float e[8];
    #pragma unroll
    for (int jj = 0; jj < 8; ++jj) {
        int j = jj * 256 + tid;
        float s = 0.f;
        #pragma unroll
        for (int d = 0; d < 10; ++d) s += qs[d] * kb[(size_t)d * Tt + j];
        e[jj] = s;
    }
    float m = e[0];
    #pragma unroll
    for (int jj = 1; jj < 8; ++jj) m = fmaxf(m, e[jj]);
    red[tid] = m; __syncthreads();
    for (int s2 = 128; s2 > 0; s2 >>= 1) {
        if (tid < s2) red[tid] = fmaxf(red[tid], red[tid + s2]);
        __syncthreads();
    }
    float M = red[0];
    __syncthreads();
    float sum = 0.f;
    #pragma unroll
    for (int jj = 0; jj < 8; ++jj) { e[jj] = __expf(e[jj] - M); sum += e[jj]; }
    red[tid] = sum; __syncthreads();
    for (int s2 = 128; s2 > 0; s2 >>= 1) {
        if (tid < s2) red[tid] += red[tid + s2];
        __syncthreads();
    }
    float inv = 1.f / red[0];
    float* arow = A + (size_t)bi * Tt;
    #pragma unroll
    for (int jj = 0; jj < 8; ++jj) arow[jj * 256 + tid] = e[jj] * inv;
}

// ---------------------------------------------------------------------------
// K5: PV.  Y[b][n][i] = sum_j x[b][n][j] * A[b][i][j]   (written into d_out)
// 128x128 tile / block, 8x8 per thread, j-tile 16.  grid (64, 16, 4)
// ---------------------------------------------------------------------------
__global__ __launch_bounds__(256) void k_pv(const float* __restrict__ x,
                                            const float* __restrict__ A,
                                            float* __restrict__ Y) {
    __shared__ float xs[16][128];
    __shared__ float as[16][128];
    int nb = blockIdx.x, ib = blockIdx.y, b = blockIdx.z;
    const float* xb = x + (size_t)b * CF * Tt + (size_t)nb * 128 * Tt;
    const float* ab = A + (size_t)b * Tt * Tt + (size_t)ib * 128 * Tt;
    int tid = threadIdx.x;
    int tr = tid >> 4, tc = tid & 15;
    float acc[8][8];
    #pragma unroll
    for (int r = 0; r < 8; ++r)
        #pragma unroll
        for (int c = 0; c < 8; ++c) acc[r][c] = 0.f;
    for (int j0 = 0; j0 < Tt; j0 += 16) {
        #pragma unroll
        for (int it = 0; it < 2; ++it) {
            int flat = tid + it * 256;       // 0..511
            int row = flat >> 2;             // 0..127
            int q4 = (flat & 3) << 2;        // 0,4,8,12
            const float4 xv = *(const float4*)(xb + (size_t)row * Tt + j0 + q4);
            xs[q4 + 0][row] = xv.x; xs[q4 + 1][row] = xv.y;
            xs[q4 + 2][row] = xv.z; xs[q4 + 3][row] = xv.w;
            const float4 av = *(const float4*)(ab + (size_t)row * Tt + j0 + q4);
            as[q4 + 0][row] = av.x; as[q4 + 1][row] = av.y;
            as[q4 + 2][row] = av.z; as[q4 + 3][row] = av.w;
        }
        __syncthreads();
        #pragma unroll
        for (int jj = 0; jj < 16; ++jj) {
            float xr[8], ar[8];
            *(float4*)&xr[0] = *(const float4*)&xs[jj][tr * 8];
            *(float4*)&xr[4] = *(const float4*)&xs[jj][tr * 8 + 4];
            *(float4*)&ar[0] = *(const float4*)&as[jj][tc * 8];
            *(float4*)&ar[4] = *(const float4*)&as[jj][tc * 8 + 4];
            #pragma unroll
            for (int r = 0; r < 8; ++r)
                #pragma unroll
                for (int c = 0; c < 8; ++c) acc[r][c] += xr[r] * ar[c];
        }
        __syncthreads();
    }
    float* yb = Y + (size_t)b * CF * Tt + (size_t)nb * 128 * Tt + (size_t)ib * 128;
    #pragma unroll
    for (int r = 0; r < 8; ++r) {
        #pragma unroll
        for (int c4 = 0; c4 < 2; ++c4) {
            float4 o;
            o.x = acc[r][c4 * 4 + 0]; o.y = acc[r][c4 * 4 + 1];
            o.z = acc[r][c4 * 4 + 2]; o.w = acc[r][c4 * 4 + 3];
            *(float4*)(yb + (size_t)(tr * 8 + r) * Tt + tc * 8 + c4 * 4) = o;
        }
    }
}

// ---------------------------------------------------------------------------
// K6: in-place channel conv on d_out.  out[b][c*64+f][i] = bv[c] + sum_c' Wv[c][c'] * Y[b][c'*64+f][i]
// Each thread owns one i-column: reads all 128 c' before writing -> in-place safe.
// grid (8, 64, 4) x 256
// ---------------------------------------------------------------------------
__global__ __launch_bounds__(256) void k_conv(const float* __restrict__ Wv,
                                              const float* __restrict__ bv,
                                              float* __restrict__ out) {
    int i = blockIdx.x * 256 + threadIdx.x;  // 0..2047
    int f = blockIdx.y;
    int b = blockIdx.z;
    float* ob = out + (size_t)b * CF * Tt + (size_t)f * Tt + i;
    float acc[128];
    #pragma unroll
    for (int c = 0; c < 128; ++c) acc[c] = bv[c];
    for (int cp = 0; cp < 128; ++cp) {
        float yv = ob[(size_t)cp * 64 * Tt];
        #pragma unroll
        for (int c = 0; c < 128; ++c) acc[c] += Wv[c * 128 + cp] * yv;  // Wv uniform -> s_load
    }
    #pragma unroll
    for (int c = 0; c < 128; ++c) ob[(size_t)c * 64 * Tt] = acc[c];
}

// ---------------------------------------------------------------------------
extern "C" void kernel_launch(void* const* d_in, const int* in_sizes, int n_in,
                              void* d_out, int out_size, void* d_ws, size_t ws_size,
                              hipStream_t stream) {
    const float* x       = (const float*)d_in[0];
    const float* Wq_conv = (const float*)d_in[1];
    const float* bq_conv = (const float*)d_in[2];
    const float* Wq_lin  = (const float*)d_in[3];
    const float* bq_lin  = (const float*)d_in[4];
    const float* Wk_conv = (const float*)d_in[5];
    const float* bk_conv = (const float*)d_in[6];
    const float* Wk_lin  = (const float*)d_in[7];
    const float* bk_lin  = (const float*)d_in[8];
    const float* Wv      = (const float*)d_in[9];
    const float* bv      = (const float*)d_in[10];
    float* out = (float*)d_out;

    float* ws   = (float*)d_ws;
    float* weff = ws;                       // 163840
    float* cqk  = weff + 163840;            // 32 (padded)
    float* part = cqk + 32;                 // 4*32*20*2048 = 5242880
    float* Qb   = part + 5242880;           // 81920
    float* Ktb  = Qb + 81920;               // 81920
    float* Ab   = Ktb + 81920;              // 16777216

    k_weff <<<640, 256, 0, stream>>>(Wq_lin, Wq_conv, Wk_lin, Wk_conv, weff);
    k_const<<<1, 32, 0, stream>>>(Wq_lin, bq_conv, bq_lin, Wk_lin, bk_conv, bk_lin, cqk);
    k_qk   <<<512, 256, 0, stream>>>(x, weff, part);
    k_qkred<<<32, 256, 0, stream>>>(part, cqk, Qb, Ktb);
    k_att  <<<8192, 256, 0, stream>>>(Qb, Ktb, Ab);
    k_pv   <<<dim3(64, 16, 4), 256, 0, stream>>>(x, Ab, out);
    k_conv <<<dim3(8, 64, 4), 256, 0, stream>>>(Wv, bv, out);
}

// Round 2
// 1579.724 us; speedup vs baseline: 2.8117x; 2.8117x over previous
//
#include <hip/hip_runtime.h>
#include <hip/hip_bf16.h>

#define Bq 4
#define Cc 128
#define Ff 64
#define Tt 2048
#define CF 8192     // C*F
#define NCHUNK 32   // cf chunks for QK pass
#define CHUNK 256   // cf per chunk

typedef __attribute__((ext_vector_type(4))) float f32x4;
typedef __attribute__((ext_vector_type(8))) short bf16x8;

__device__ inline ushort f2bf(float f) {
    __hip_bfloat16 h = __float2bfloat16(f);   // round-to-nearest
    return *reinterpret_cast<ushort*>(&h);
}

__device__ inline void gload_lds16(const void* g, void* l) {
    __builtin_amdgcn_global_load_lds(
        (const __attribute__((address_space(1))) void*)g,
        (__attribute__((address_space(3))) void*)l, 16, 0, 0);
}

// ---------------------------------------------------------------------------
// K1: effective QK weights  Weff[cf][d] (d<10: q, d>=10: k), cf = c*64+f
// ---------------------------------------------------------------------------
__global__ void k_weff(const float* __restrict__ Wq_lin, const float* __restrict__ Wq_conv,
                       const float* __restrict__ Wk_lin, const float* __restrict__ Wk_conv,
                       float* __restrict__ weff) {
    int gid = blockIdx.x * 256 + threadIdx.x;
    if (gid >= CF * 20) return;
    int cf = gid / 20, d = gid % 20;
    int c = cf >> 6, f = cf & 63;
    float s = 0.f;
    if (d < 10) {
        #pragma unroll
        for (int o = 0; o < 4; ++o) s += Wq_lin[d * 256 + o * 64 + f] * Wq_conv[o * 128 + c];
    } else {
        int dd = d - 10;
        #pragma unroll
        for (int o = 0; o < 4; ++o) s += Wk_lin[dd * 256 + o * 64 + f] * Wk_conv[o * 128 + c];
    }
    weff[cf * 20 + d] = s;
}

// K1b: constants  cqk[d] = b_lin[d] + sum_{o,f} W_lin[d][o*64+f] * b_conv[o]
__global__ void k_const(const float* __restrict__ Wq_lin, const float* __restrict__ bq_conv,
                        const float* __restrict__ bq_lin, const float* __restrict__ Wk_lin,
                        const float* __restrict__ bk_conv, const float* __restrict__ bk_lin,
                        float* __restrict__ cqk) {
    int d = threadIdx.x;
    if (d >= 20) return;
    float s;
    if (d < 10) {
        s = bq_lin[d];
        for (int o = 0; o < 4; ++o) {
            float bb = bq_conv[o];
            for (int f = 0; f < 64; ++f) s += Wq_lin[d * 256 + o * 64 + f] * bb;
        }
    } else {
        int dd = d - 10;
        s = bk_lin[dd];
        for (int o = 0; o < 4; ++o) {
            float bb = bk_conv[o];
            for (int f = 0; f < 64; ++f) s += Wk_lin[dd * 256 + o * 64 + f] * bb;
        }
    }
    cqk[d] = s;
}

// ---------------------------------------------------------------------------
// K1c: x -> bf16  (67.1M elems, 8 per thread)
// ---------------------------------------------------------------------------
__global__ __launch_bounds__(256) void k_xbf(const float* __restrict__ x,
                                             ushort* __restrict__ xb) {
    int i = blockIdx.x * 256 + threadIdx.x;          // 0 .. 8388607 (8 elems each)
    float4 a = ((const float4*)x)[(size_t)i * 2];
    float4 b2 = ((const float4*)x)[(size_t)i * 2 + 1];
    ushort4 lo = make_ushort4(f2bf(a.x), f2bf(a.y), f2bf(a.z), f2bf(a.w));
    ushort4 hi = make_ushort4(f2bf(b2.x), f2bf(b2.y), f2bf(b2.z), f2bf(b2.w));
    ((ushort4*)xb)[(size_t)i * 2] = lo;
    ((ushort4*)xb)[(size_t)i * 2 + 1] = hi;
}

// ---------------------------------------------------------------------------
// K2: QK partials.  partial[b][ch][d][t] = sum_{cf in chunk} x[b][cf][t]*Weff[cf][d]
// ---------------------------------------------------------------------------
__global__ __launch_bounds__(256) void k_qk(const float* __restrict__ x,
                                            const float* __restrict__ weff,
                                            float* __restrict__ partial) {
    int blk = blockIdx.x;
    int tt = blk & 3;
    int ch = (blk >> 2) & 31;
    int b  = blk >> 7;
    int t = tt * 512 + threadIdx.x * 2;
    const float* xb = x + (size_t)b * CF * Tt;
    float acc[20][2];
    #pragma unroll
    for (int d = 0; d < 20; ++d) { acc[d][0] = 0.f; acc[d][1] = 0.f; }
    int cf0 = ch * CHUNK;
    for (int cf = cf0; cf < cf0 + CHUNK; ++cf) {
        float2 xv = *(const float2*)(xb + (size_t)cf * Tt + t);
        const float* w = weff + cf * 20;   // uniform address -> s_loads
        #pragma unroll
        for (int d = 0; d < 20; ++d) {
            float wv = w[d];
            acc[d][0] += wv * xv.x;
            acc[d][1] += wv * xv.y;
        }
    }
    float* pb = partial + (size_t)(b * NCHUNK + ch) * 20 * Tt;
    #pragma unroll
    for (int d = 0; d < 20; ++d)
        *(float2*)(pb + (size_t)d * Tt + t) = make_float2(acc[d][0], acc[d][1]);
}

// K3: reduce partials + const -> Q[b][t][10], Kt[b][10][t].  grid 32 x 256
__global__ void k_qkred(const float* __restrict__ partial, const float* __restrict__ cqk,
                        float* __restrict__ Q, float* __restrict__ Kt) {
    int t = blockIdx.x * 256 + threadIdx.x;  // 0..8191
    int b = t >> 11, tl = t & 2047;
    for (int d = 0; d < 20; ++d) {
        float s = cqk[d];
        for (int ch = 0; ch < NCHUNK; ++ch)
            s += partial[((size_t)(b * NCHUNK + ch) * 20 + d) * Tt + tl];
        if (d < 10) Q[(size_t)(b * 2048 + tl) * 10 + d] = s;
        else        Kt[((size_t)b * 10 + (d - 10)) * Tt + tl] = s;
    }
}

// ---------------------------------------------------------------------------
// K4: energy + softmax -> A_bf16[b][i][j].  block per (b,i): 8192 blocks x 256
// ---------------------------------------------------------------------------
__global__ __launch_bounds__(256) void k_att(const float* __restrict__ Q,
                                             const float* __restrict__ Kt,
                                             ushort* __restrict__ A) {
    int bi = blockIdx.x;
    int b = bi >> 11;
    __shared__ float qs[10];
    __shared__ float red[256];
    int tid = threadIdx.x;
    if (tid < 10) qs[tid] = Q[(size_t)bi * 10 + tid];
    __syncthreads();
    const float* kb = Kt + (size_t)b * 10 * Tt;
    float e[8];
    #pragma unroll
    for (int jj = 0; jj < 8; ++jj) {
        int j = jj * 256 + tid;
        float s = 0.f;
        #pragma unroll
        for (int d = 0; d < 10; ++d) s += qs[d] * kb[(size_t)d * Tt + j];
        e[jj] = s;
    }
    float m = e[0];
    #pragma unroll
    for (int jj = 1; jj < 8; ++jj) m = fmaxf(m, e[jj]);
    red[tid] = m; __syncthreads();
    for (int s2 = 128; s2 > 0; s2 >>= 1) {
        if (tid < s2) red[tid] = fmaxf(red[tid], red[tid + s2]);
        __syncthreads();
    }
    float M = red[0];
    __syncthreads();
    float sum = 0.f;
    #pragma unroll
    for (int jj = 0; jj < 8; ++jj) { e[jj] = __expf(e[jj] - M); sum += e[jj]; }
    red[tid] = sum; __syncthreads();
    for (int s2 = 128; s2 > 0; s2 >>= 1) {
        if (tid < s2) red[tid] += red[tid + s2];
        __syncthreads();
    }
    float inv = 1.f / red[0];
    ushort* arow = A + (size_t)bi * Tt;
    #pragma unroll
    for (int jj = 0; jj < 8; ++jj) arow[jj * 256 + tid] = f2bf(e[jj] * inv);
}

// ---------------------------------------------------------------------------
// K5: PV via MFMA (m97 structure).  Y[b][n][i] = sum_j Xb[b][n][j] * Ab[b][i][j]
// 128x128 tile, BK=32, 4 waves, 4x4 mfma_f32_16x16x32_bf16 per wave.
// grid (64, 16, 4) x 256
// ---------------------------------------------------------------------------
__global__ __launch_bounds__(256) void k_pv_mfma(const ushort* __restrict__ Xb,
                                                 const ushort* __restrict__ Ab,
                                                 float* __restrict__ Y) {
    __shared__ ushort As[128 * 32];
    __shared__ ushort Bs[128 * 32];
    int nb = blockIdx.x, ib = blockIdx.y, b = blockIdx.z;
    const ushort* xb = Xb + (size_t)b * CF * Tt + (size_t)nb * 128 * Tt;
    const ushort* ab = Ab + (size_t)b * Tt * Tt + (size_t)ib * 128 * Tt;
    int tid = threadIdx.x;
    int w = tid >> 6, l = tid & 63;
    int wr = w >> 1, wc = w & 1;

    // staging addresses: wave w stages rows [w*32, w*32+32)
    int srow = w * 32 + (l >> 2);
    int scol = (l & 3) * 8;                       // bf16 offset within BK
    const ushort* xs0 = xb + (size_t)srow * Tt + scol;
    const ushort* xs1 = xs0 + 16 * Tt;
    const ushort* as0 = ab + (size_t)srow * Tt + scol;
    const ushort* as1 = as0 + 16 * Tt;
    ushort* ldsA0 = As + w * 1024;
    ushort* ldsA1 = As + w * 1024 + 512;
    ushort* ldsB0 = Bs + w * 1024;
    ushort* ldsB1 = Bs + w * 1024 + 512;

    f32x4 acc[4][4];
    #pragma unroll
    for (int m = 0; m < 4; ++m)
        #pragma unroll
        for (int n = 0; n < 4; ++n) acc[m][n] = (f32x4){0.f, 0.f, 0.f, 0.f};

    int arow_l = (l & 15);        // row-in-16 for fragments
    int koff = (l >> 4) * 8;      // k offset for fragments

    for (int k0 = 0; k0 < Tt; k0 += 32) {
        gload_lds16(xs0 + k0, ldsA0);
        gload_lds16(xs1 + k0, ldsA1);
        gload_lds16(as0 + k0, ldsB0);
        gload_lds16(as1 + k0, ldsB1);
        __syncthreads();
        bf16x8 afr[4], bfr[4];
        #pragma unroll
        for (int m = 0; m < 4; ++m)
            afr[m] = *(const bf16x8*)&As[(wr * 64 + m * 16 + arow_l) * 32 + koff];
        #pragma unroll
        for (int n = 0; n < 4; ++n)
            bfr[n] = *(const bf16x8*)&Bs[(wc * 64 + n * 16 + arow_l) * 32 + koff];
        #pragma unroll
        for (int m = 0; m < 4; ++m)
            #pragma unroll
            for (int n = 0; n < 4; ++n)
                acc[m][n] = __builtin_amdgcn_mfma_f32_16x16x32_bf16(afr[m], bfr[n], acc[m][n], 0, 0, 0);
        __syncthreads();
    }

    float* yb = Y + (size_t)b * CF * Tt + (size_t)(nb * 128) * Tt + (size_t)ib * 128;
    int ccol = wc * 64 + (l & 15);
    int rbase = wr * 64 + (l >> 4) * 4;
    #pragma unroll
    for (int m = 0; m < 4; ++m) {
        #pragma unroll
        for (int n = 0; n < 4; ++n) {
            #pragma unroll
            for (int r = 0; r < 4; ++r) {
                int row = rbase + m * 16 + r;
                int col = ccol + n * 16;
                yb[(size_t)row * Tt + col] = acc[m][n][r];
            }
        }
    }
}

// ---------------------------------------------------------------------------
// K6: in-place channel conv on d_out.
// ---------------------------------------------------------------------------
__global__ __launch_bounds__(256) void k_conv(const float* __restrict__ Wv,
                                              const float* __restrict__ bv,
                                              float* __restrict__ out) {
    int i = blockIdx.x * 256 + threadIdx.x;  // 0..2047
    int f = blockIdx.y;
    int b = blockIdx.z;
    float* ob = out + (size_t)b * CF * Tt + (size_t)f * Tt + i;
    float acc[128];
    #pragma unroll
    for (int c = 0; c < 128; ++c) acc[c] = bv[c];
    for (int cp = 0; cp < 128; ++cp) {
        float yv = ob[(size_t)cp * 64 * Tt];
        #pragma unroll
        for (int c = 0; c < 128; ++c) acc[c] += Wv[c * 128 + cp] * yv;
    }
    #pragma unroll
    for (int c = 0; c < 128; ++c) ob[(size_t)c * 64 * Tt] = acc[c];
}

// ---------------------------------------------------------------------------
extern "C" void kernel_launch(void* const* d_in, const int* in_sizes, int n_in,
                              void* d_out, int out_size, void* d_ws, size_t ws_size,
                              hipStream_t stream) {
    const float* x       = (const float*)d_in[0];
    const float* Wq_conv = (const float*)d_in[1];
    const float* bq_conv = (const float*)d_in[2];
    const float* Wq_lin  = (const float*)d_in[3];
    const float* bq_lin  = (const float*)d_in[4];
    const float* Wk_conv = (const float*)d_in[5];
    const float* bk_conv = (const float*)d_in[6];
    const float* Wk_lin  = (const float*)d_in[7];
    const float* bk_lin  = (const float*)d_in[8];
    const float* Wv      = (const float*)d_in[9];
    const float* bv      = (const float*)d_in[10];
    float* out = (float*)d_out;

    float* ws   = (float*)d_ws;
    float* weff = ws;                         // 163840
    float* cqk  = weff + 163840;              // 32
    float* part = cqk + 32;                   // 5242880
    float* Qb   = part + 5242880;             // 81920
    float* Ktb  = Qb + 81920;                 // 81920
    float* Abf_f = Ktb + 81920;               // 8388608 floats = 16.7M bf16
    float* Xbf_f = Abf_f + 8388608;           // 33554432 floats = 67.1M bf16
    ushort* Abf = (ushort*)Abf_f;
    ushort* Xbf = (ushort*)Xbf_f;

    k_weff <<<640, 256, 0, stream>>>(Wq_lin, Wq_conv, Wk_lin, Wk_conv, weff);
    k_const<<<1, 32, 0, stream>>>(Wq_lin, bq_conv, bq_lin, Wk_lin, bk_conv, bk_lin, cqk);
    k_xbf  <<<32768, 256, 0, stream>>>(x, Xbf);
    k_qk   <<<512, 256, 0, stream>>>(x, weff, part);
    k_qkred<<<32, 256, 0, stream>>>(part, cqk, Qb, Ktb);
    k_att  <<<8192, 256, 0, stream>>>(Qb, Ktb, Abf);
    k_pv_mfma<<<dim3(64, 16, 4), 256, 0, stream>>>(Xbf, Abf, out);
    k_conv <<<dim3(8, 64, 4), 256, 0, stream>>>(Wv, bv, out);
}

// Round 3
// 764.226 us; speedup vs baseline: 5.8120x; 2.0671x over previous
//
#include <hip/hip_runtime.h>
#include <hip/hip_bf16.h>

#define Bq 4
#define Cc 128
#define Ff 64
#define Tt 2048
#define CF 8192     // C*F
#define NCHUNK 32   // cf chunks for QK pass
#define CHUNK 256   // cf per chunk

typedef __attribute__((ext_vector_type(4))) float f32x4;
typedef __attribute__((ext_vector_type(8))) short bf16x8;

__device__ inline ushort f2bf(float f) {
    __hip_bfloat16 h = __float2bfloat16(f);   // round-to-nearest
    return *reinterpret_cast<ushort*>(&h);
}

__device__ inline void gload_lds16(const void* g, void* l) {
    __builtin_amdgcn_global_load_lds(
        (const __attribute__((address_space(1))) void*)g,
        (__attribute__((address_space(3))) void*)l, 16, 0, 0);
}

// ---------------------------------------------------------------------------
// K1: effective QK weights  Weff[cf][d] (d<10: q, d>=10: k), cf = c*64+f
// ---------------------------------------------------------------------------
__global__ void k_weff(const float* __restrict__ Wq_lin, const float* __restrict__ Wq_conv,
                       const float* __restrict__ Wk_lin, const float* __restrict__ Wk_conv,
                       float* __restrict__ weff) {
    int gid = blockIdx.x * 256 + threadIdx.x;
    if (gid >= CF * 20) return;
    int cf = gid / 20, d = gid % 20;
    int c = cf >> 6, f = cf & 63;
    float s = 0.f;
    if (d < 10) {
        #pragma unroll
        for (int o = 0; o < 4; ++o) s += Wq_lin[d * 256 + o * 64 + f] * Wq_conv[o * 128 + c];
    } else {
        int dd = d - 10;
        #pragma unroll
        for (int o = 0; o < 4; ++o) s += Wk_lin[dd * 256 + o * 64 + f] * Wk_conv[o * 128 + c];
    }
    weff[cf * 20 + d] = s;
}

// K1b: constants  cqk[d] = b_lin[d] + sum_{o,f} W_lin[d][o*64+f] * b_conv[o]
__global__ void k_const(const float* __restrict__ Wq_lin, const float* __restrict__ bq_conv,
                        const float* __restrict__ bq_lin, const float* __restrict__ Wk_lin,
                        const float* __restrict__ bk_conv, const float* __restrict__ bk_lin,
                        float* __restrict__ cqk) {
    int d = threadIdx.x;
    if (d >= 20) return;
    float s;
    if (d < 10) {
        s = bq_lin[d];
        for (int o = 0; o < 4; ++o) {
            float bb = bq_conv[o];
            for (int f = 0; f < 64; ++f) s += Wq_lin[d * 256 + o * 64 + f] * bb;
        }
    } else {
        int dd = d - 10;
        s = bk_lin[dd];
        for (int o = 0; o < 4; ++o) {
            float bb = bk_conv[o];
            for (int f = 0; f < 64; ++f) s += Wk_lin[dd * 256 + o * 64 + f] * bb;
        }
    }
    cqk[d] = s;
}

// K1d: Wv -> bf16 (16384 elems)
__global__ void k_wvb(const float* __restrict__ Wv, ushort* __restrict__ Wvb) {
    int i = blockIdx.x * 256 + threadIdx.x;
    if (i < 16384) Wvb[i] = f2bf(Wv[i]);
}

// ---------------------------------------------------------------------------
// K2: QK partials + x->bf16 side-write.
// partial[b][ch][d][t] = sum_{cf in chunk} x[b][cf][t]*Weff[cf][d]
// ---------------------------------------------------------------------------
__global__ __launch_bounds__(256) void k_qk(const float* __restrict__ x,
                                            const float* __restrict__ weff,
                                            float* __restrict__ partial,
                                            ushort* __restrict__ xbf) {
    int blk = blockIdx.x;
    int tt = blk & 3;
    int ch = (blk >> 2) & 31;
    int b  = blk >> 7;
    int t = tt * 512 + threadIdx.x * 2;
    const float* xb = x + (size_t)b * CF * Tt;
    ushort* xob = xbf + (size_t)b * CF * Tt;
    float acc[20][2];
    #pragma unroll
    for (int d = 0; d < 20; ++d) { acc[d][0] = 0.f; acc[d][1] = 0.f; }
    int cf0 = ch * CHUNK;
    for (int cf = cf0; cf < cf0 + CHUNK; ++cf) {
        float2 xv = *(const float2*)(xb + (size_t)cf * Tt + t);
        *(ushort2*)(xob + (size_t)cf * Tt + t) = make_ushort2(f2bf(xv.x), f2bf(xv.y));
        const float* w = weff + cf * 20;   // uniform address -> s_loads
        #pragma unroll
        for (int d = 0; d < 20; ++d) {
            float wv = w[d];
            acc[d][0] += wv * xv.x;
            acc[d][1] += wv * xv.y;
        }
    }
    float* pb = partial + (size_t)(b * NCHUNK + ch) * 20 * Tt;
    #pragma unroll
    for (int d = 0; d < 20; ++d)
        *(float2*)(pb + (size_t)d * Tt + t) = make_float2(acc[d][0], acc[d][1]);
}

// K3: reduce partials + const -> Q[b][t][10], Kt[b][10][t].  grid 32 x 256
__global__ void k_qkred(const float* __restrict__ partial, const float* __restrict__ cqk,
                        float* __restrict__ Q, float* __restrict__ Kt) {
    int t = blockIdx.x * 256 + threadIdx.x;  // 0..8191
    int b = t >> 11, tl = t & 2047;
    for (int d = 0; d < 20; ++d) {
        float s = cqk[d];
        for (int ch = 0; ch < NCHUNK; ++ch)
            s += partial[((size_t)(b * NCHUNK + ch) * 20 + d) * Tt + tl];
        if (d < 10) Q[(size_t)(b * 2048 + tl) * 10 + d] = s;
        else        Kt[((size_t)b * 10 + (d - 10)) * Tt + tl] = s;
    }
}

// ---------------------------------------------------------------------------
// K4: energy + softmax -> A_bf16[b][i][j].  block per (b,i): 8192 blocks x 256
// ---------------------------------------------------------------------------
__global__ __launch_bounds__(256) void k_att(const float* __restrict__ Q,
                                             const float* __restrict__ Kt,
                                             ushort* __restrict__ A) {
    int bi = blockIdx.x;
    int b = bi >> 11;
    __shared__ float qs[10];
    __shared__ float red[256];
    int tid = threadIdx.x;
    if (tid < 10) qs[tid] = Q[(size_t)bi * 10 + tid];
    __syncthreads();
    const float* kb = Kt + (size_t)b * 10 * Tt;
    float e[8];
    #pragma unroll
    for (int jj = 0; jj < 8; ++jj) {
        int j = jj * 256 + tid;
        float s = 0.f;
        #pragma unroll
        for (int d = 0; d < 10; ++d) s += qs[d] * kb[(size_t)d * Tt + j];
        e[jj] = s;
    }
    float m = e[0];
    #pragma unroll
    for (int jj = 1; jj < 8; ++jj) m = fmaxf(m, e[jj]);
    red[tid] = m; __syncthreads();
    for (int s2 = 128; s2 > 0; s2 >>= 1) {
        if (tid < s2) red[tid] = fmaxf(red[tid], red[tid + s2]);
        __syncthreads();
    }
    float M = red[0];
    __syncthreads();
    float sum = 0.f;
    #pragma unroll
    for (int jj = 0; jj < 8; ++jj) { e[jj] = __expf(e[jj] - M); sum += e[jj]; }
    red[tid] = sum; __syncthreads();
    for (int s2 = 128; s2 > 0; s2 >>= 1) {
        if (tid < s2) red[tid] += red[tid + s2];
        __syncthreads();
    }
    float inv = 1.f / red[0];
    ushort* arow = A + (size_t)bi * Tt;
    #pragma unroll
    for (int jj = 0; jj < 8; ++jj) arow[jj * 256 + tid] = f2bf(e[jj] * inv);
}

// ---------------------------------------------------------------------------
// K5: fused PV + channel conv.
// Block owns: fixed f, i-tile of 128, batch b.  Rows n = c'*64+f, c' in [0,128).
//  Stage 1 (PV):    Ytile[c'][i] = sum_j Xb[b][c'*64+f][j] * Ab[b][i0+i][j]   (MFMA, K=2048)
//  transpose:       Yt[i][c'] in LDS (bf16, byte ^= (i&7)<<4 swizzle)
//  Stage 2 (conv):  out[b][c*64+f][i0+i] = bv[c] + sum_c' Wvb[c][c'] * Yt[i][c']  (MFMA, K=128)
// grid (64 f, 16 i-tiles, 4 b) x 256
// ---------------------------------------------------------------------------
__global__ __launch_bounds__(256) void k_pv_conv(const ushort* __restrict__ Xb,
                                                 const ushort* __restrict__ Ab,
                                                 const ushort* __restrict__ Wvb,
                                                 const float* __restrict__ bv,
                                                 float* __restrict__ out) {
    __shared__ ushort As[128 * 32];
    __shared__ ushort Bs[128 * 32];
    __shared__ ushort Yt[128 * 128];
    int f = blockIdx.x, ib = blockIdx.y, b = blockIdx.z;
    const ushort* xb = Xb + (size_t)b * CF * Tt + (size_t)f * Tt;   // c' row stride 64*Tt
    const ushort* ab = Ab + (size_t)b * Tt * Tt + (size_t)ib * 128 * Tt;
    int tid = threadIdx.x;
    int w = tid >> 6, l = tid & 63;
    int wr = w >> 1, wc = w & 1;

    // staging: wave w stages c'-rows [w*32, w*32+32) of X and i-rows of A
    int srow = w * 32 + (l >> 2);
    int scol = (l & 3) * 8;
    const ushort* xs0 = xb + (size_t)srow * 64 * Tt + scol;
    const ushort* xs1 = xs0 + (size_t)16 * 64 * Tt;
    const ushort* as0 = ab + (size_t)srow * Tt + scol;
    const ushort* as1 = as0 + (size_t)16 * Tt;
    ushort* ldsA0 = As + w * 1024;
    ushort* ldsA1 = As + w * 1024 + 512;
    ushort* ldsB0 = Bs + w * 1024;
    ushort* ldsB1 = Bs + w * 1024 + 512;

    f32x4 acc[4][4];
    #pragma unroll
    for (int m = 0; m < 4; ++m)
        #pragma unroll
        for (int n = 0; n < 4; ++n) acc[m][n] = (f32x4){0.f, 0.f, 0.f, 0.f};

    int frow = (l & 15);
    int koff = (l >> 4) * 8;

    for (int k0 = 0; k0 < Tt; k0 += 32) {
        gload_lds16(xs0 + k0, ldsA0);
        gload_lds16(xs1 + k0, ldsA1);
        gload_lds16(as0 + k0, ldsB0);
        gload_lds16(as1 + k0, ldsB1);
        __syncthreads();
        bf16x8 afr[4], bfr[4];
        #pragma unroll
        for (int m = 0; m < 4; ++m)
            afr[m] = *(const bf16x8*)&As[(wr * 64 + m * 16 + frow) * 32 + koff];
        #pragma unroll
        for (int n = 0; n < 4; ++n)
            bfr[n] = *(const bf16x8*)&Bs[(wc * 64 + n * 16 + frow) * 32 + koff];
        #pragma unroll
        for (int m = 0; m < 4; ++m)
            #pragma unroll
            for (int n = 0; n < 4; ++n)
                acc[m][n] = __builtin_amdgcn_mfma_f32_16x16x32_bf16(afr[m], bfr[n], acc[m][n], 0, 0, 0);
        __syncthreads();
    }

    // ---- transpose acc -> Yt[i][c'] (bf16, swizzled) ----
    // acc[m][n][r] = Y[c' = wr*64 + m*16 + (l>>4)*4 + r][i = wc*64 + n*16 + (l&15)]
    int rbase = wr * 64 + ((l >> 4) << 2);
    #pragma unroll
    for (int n = 0; n < 4; ++n) {
        int i = wc * 64 + n * 16 + (l & 15);
        int swz = (i & 7) << 4;
        #pragma unroll
        for (int m = 0; m < 4; ++m) {
            int cp = rbase + m * 16;
            ushort4 v;
            v.x = f2bf(acc[m][n][0]); v.y = f2bf(acc[m][n][1]);
            v.z = f2bf(acc[m][n][2]); v.w = f2bf(acc[m][n][3]);
            *(ushort4*)((char*)Yt + (((i << 8) + (cp << 1)) ^ swz)) = v;
        }
    }
    __syncthreads();

    // ---- stage 2: Out[c][i] = sum_c' Wvb[c][c'] * Yt[i][c'], K=128 ----
    f32x4 acc2[4][4];
    #pragma unroll
    for (int m = 0; m < 4; ++m)
        #pragma unroll
        for (int n = 0; n < 4; ++n) acc2[m][n] = (f32x4){0.f, 0.f, 0.f, 0.f};
    #pragma unroll
    for (int ks = 0; ks < 4; ++ks) {
        int kofs = ks * 32 + koff;
        bf16x8 afr[4], bfr[4];
        #pragma unroll
        for (int m = 0; m < 4; ++m) {
            int c = wr * 64 + m * 16 + frow;
            afr[m] = *(const bf16x8*)&Wvb[c * 128 + kofs];
        }
        #pragma unroll
        for (int n = 0; n < 4; ++n) {
            int i = wc * 64 + n * 16 + frow;
            bfr[n] = *(const bf16x8*)((const char*)Yt + (((i << 8) + (kofs << 1)) ^ ((i & 7) << 4)));
        }
        #pragma unroll
        for (int m = 0; m < 4; ++m)
            #pragma unroll
            for (int n = 0; n < 4; ++n)
                acc2[m][n] = __builtin_amdgcn_mfma_f32_16x16x32_bf16(afr[m], bfr[n], acc2[m][n], 0, 0, 0);
    }

    // ---- bias + write d_out ----
    float* ob = out + (size_t)b * CF * Tt + (size_t)f * Tt + (size_t)ib * 128;
    #pragma unroll
    for (int m = 0; m < 4; ++m) {
        #pragma unroll
        for (int r = 0; r < 4; ++r) {
            int c = wr * 64 + m * 16 + ((l >> 4) << 2) + r;
            float bvv = bv[c];
            #pragma unroll
            for (int n = 0; n < 4; ++n) {
                int col = wc * 64 + n * 16 + (l & 15);
                ob[(size_t)c * 64 * Tt + col] = acc2[m][n][r] + bvv;
            }
        }
    }
}

// ---------------------------------------------------------------------------
extern "C" void kernel_launch(void* const* d_in, const int* in_sizes, int n_in,
                              void* d_out, int out_size, void* d_ws, size_t ws_size,
                              hipStream_t stream) {
    const float* x       = (const float*)d_in[0];
    const float* Wq_conv = (const float*)d_in[1];
    const float* bq_conv = (const float*)d_in[2];
    const float* Wq_lin  = (const float*)d_in[3];
    const float* bq_lin  = (const float*)d_in[4];
    const float* Wk_conv = (const float*)d_in[5];
    const float* bk_conv = (const float*)d_in[6];
    const float* Wk_lin  = (const float*)d_in[7];
    const float* bk_lin  = (const float*)d_in[8];
    const float* Wv      = (const float*)d_in[9];
    const float* bv      = (const float*)d_in[10];
    float* out = (float*)d_out;

    float* ws   = (float*)d_ws;
    float* weff = ws;                         // 163840
    float* cqk  = weff + 163840;              // 32
    float* part = cqk + 32;                   // 5242880
    float* Qb   = part + 5242880;             // 81920
    float* Ktb  = Qb + 81920;                 // 81920
    float* Abf_f = Ktb + 81920;               // 8388608 floats = 16.7M bf16
    float* Xbf_f = Abf_f + 8388608;           // 33554432 floats = 67.1M bf16
    float* Wvb_f = Xbf_f + 33554432;          // 8192 floats = 16384 bf16
    ushort* Abf = (ushort*)Abf_f;
    ushort* Xbf = (ushort*)Xbf_f;
    ushort* Wvb = (ushort*)Wvb_f;

    k_weff <<<640, 256, 0, stream>>>(Wq_lin, Wq_conv, Wk_lin, Wk_conv, weff);
    k_const<<<1, 32, 0, stream>>>(Wq_lin, bq_conv, bq_lin, Wk_lin, bk_conv, bk_lin, cqk);
    k_wvb  <<<64, 256, 0, stream>>>(Wv, Wvb);
    k_qk   <<<512, 256, 0, stream>>>(x, weff, part, Xbf);
    k_qkred<<<32, 256, 0, stream>>>(part, cqk, Qb, Ktb);
    k_att  <<<8192, 256, 0, stream>>>(Qb, Ktb, Abf);
    k_pv_conv<<<dim3(64, 16, 4), 256, 0, stream>>>(Xbf, Abf, Wvb, bv, out);
}

// Round 4
// 597.551 us; speedup vs baseline: 7.4331x; 1.2789x over previous
//
#include <hip/hip_runtime.h>
#include <hip/hip_bf16.h>

#define Bq 4
#define Cc 128
#define Ff 64
#define Tt 2048
#define CF 8192     // C*F
#define NCHUNK 32   // cf chunks for QK pass
#define CHUNK 256   // cf per chunk

typedef __attribute__((ext_vector_type(4))) float f32x4;
typedef __attribute__((ext_vector_type(8))) short bf16x8;

__device__ inline ushort f2bf(float f) {
    __hip_bfloat16 h = __float2bfloat16(f);   // round-to-nearest
    return *reinterpret_cast<ushort*>(&h);
}

__device__ inline void gload_lds16(const void* g, void* l) {
    __builtin_amdgcn_global_load_lds(
        (const __attribute__((address_space(1))) void*)g,
        (__attribute__((address_space(3))) void*)l, 16, 0, 0);
}

// ---------------------------------------------------------------------------
// K1: merged prep.
//  blocks [0,640):   weff[cf][d]  (d<10: q, d>=10: k), cf = c*64+f
//  blocks [640,704): Wv -> bf16
//  block  704:       cqk constants
// ---------------------------------------------------------------------------
__global__ void k_prep(const float* __restrict__ Wq_lin, const float* __restrict__ Wq_conv,
                       const float* __restrict__ Wk_lin, const float* __restrict__ Wk_conv,
                       const float* __restrict__ bq_conv, const float* __restrict__ bq_lin,
                       const float* __restrict__ bk_conv, const float* __restrict__ bk_lin,
                       const float* __restrict__ Wv,
                       float* __restrict__ weff, float* __restrict__ cqk,
                       ushort* __restrict__ Wvb) {
    int blk = blockIdx.x;
    if (blk < 640) {
        int gid = blk * 256 + threadIdx.x;
        if (gid >= CF * 20) return;
        int cf = gid / 20, d = gid % 20;
        int c = cf >> 6, f = cf & 63;
        float s = 0.f;
        if (d < 10) {
            #pragma unroll
            for (int o = 0; o < 4; ++o) s += Wq_lin[d * 256 + o * 64 + f] * Wq_conv[o * 128 + c];
        } else {
            int dd = d - 10;
            #pragma unroll
            for (int o = 0; o < 4; ++o) s += Wk_lin[dd * 256 + o * 64 + f] * Wk_conv[o * 128 + c];
        }
        weff[cf * 20 + d] = s;
    } else if (blk < 704) {
        int i = (blk - 640) * 256 + threadIdx.x;
        if (i < 16384) Wvb[i] = f2bf(Wv[i]);
    } else {
        int d = threadIdx.x;
        if (d >= 20) return;
        float s;
        if (d < 10) {
            s = bq_lin[d];
            for (int o = 0; o < 4; ++o) {
                float bb = bq_conv[o];
                for (int f = 0; f < 64; ++f) s += Wq_lin[d * 256 + o * 64 + f] * bb;
            }
        } else {
            int dd = d - 10;
            s = bk_lin[dd];
            for (int o = 0; o < 4; ++o) {
                float bb = bk_conv[o];
                for (int f = 0; f < 64; ++f) s += Wk_lin[dd * 256 + o * 64 + f] * bb;
            }
        }
        cqk[d] = s;
    }
}

// ---------------------------------------------------------------------------
// K2: QK partials + x->bf16 side-write.
// partial[b][ch][d][t] = sum_{cf in chunk} x[b][cf][t]*Weff[cf][d]
// ---------------------------------------------------------------------------
__global__ __launch_bounds__(256) void k_qk(const float* __restrict__ x,
                                            const float* __restrict__ weff,
                                            float* __restrict__ partial,
                                            ushort* __restrict__ xbf) {
    int blk = blockIdx.x;
    int tt = blk & 3;
    int ch = (blk >> 2) & 31;
    int b  = blk >> 7;
    int t = tt * 512 + threadIdx.x * 2;
    const float* xb = x + (size_t)b * CF * Tt;
    ushort* xob = xbf + (size_t)b * CF * Tt;
    float acc[20][2];
    #pragma unroll
    for (int d = 0; d < 20; ++d) { acc[d][0] = 0.f; acc[d][1] = 0.f; }
    int cf0 = ch * CHUNK;
    for (int cf = cf0; cf < cf0 + CHUNK; ++cf) {
        float2 xv = *(const float2*)(xb + (size_t)cf * Tt + t);
        *(ushort2*)(xob + (size_t)cf * Tt + t) = make_ushort2(f2bf(xv.x), f2bf(xv.y));
        const float* w = weff + cf * 20;   // uniform address -> s_loads
        #pragma unroll
        for (int d = 0; d < 20; ++d) {
            float wv = w[d];
            acc[d][0] += wv * xv.x;
            acc[d][1] += wv * xv.y;
        }
    }
    float* pb = partial + (size_t)(b * NCHUNK + ch) * 20 * Tt;
    #pragma unroll
    for (int d = 0; d < 20; ++d)
        *(float2*)(pb + (size_t)d * Tt + t) = make_float2(acc[d][0], acc[d][1]);
}

// K3: reduce partials + const -> Q[b][t][10], Kt[b][10][t].  grid (32,20) x 256
__global__ void k_qkred(const float* __restrict__ partial, const float* __restrict__ cqk,
                        float* __restrict__ Q, float* __restrict__ Kt) {
    int t = blockIdx.x * 256 + threadIdx.x;  // 0..8191
    int d = blockIdx.y;                      // 0..19
    int b = t >> 11, tl = t & 2047;
    float s = cqk[d];
    #pragma unroll 4
    for (int ch = 0; ch < NCHUNK; ++ch)
        s += partial[((size_t)(b * NCHUNK + ch) * 20 + d) * Tt + tl];
    if (d < 10) Q[(size_t)(b * 2048 + tl) * 10 + d] = s;
    else        Kt[((size_t)b * 10 + (d - 10)) * Tt + tl] = s;
}

// ---------------------------------------------------------------------------
// K4: energy + softmax -> A_bf16[b][i][j].  block per (b,i): 8192 blocks x 256
// wave-shuffle reductions (2 barriers instead of 16)
// ---------------------------------------------------------------------------
__global__ __launch_bounds__(256) void k_att(const float* __restrict__ Q,
                                             const float* __restrict__ Kt,
                                             ushort* __restrict__ A) {
    int bi = blockIdx.x;
    int b = bi >> 11;
    __shared__ float qs[10];
    __shared__ float wmax[4];
    __shared__ float wsum[4];
    int tid = threadIdx.x;
    int lane = tid & 63, wid = tid >> 6;
    if (tid < 10) qs[tid] = Q[(size_t)bi * 10 + tid];
    __syncthreads();
    float q[10];
    #pragma unroll
    for (int d = 0; d < 10; ++d) q[d] = qs[d];
    const float* kb = Kt + (size_t)b * 10 * Tt;
    float e[8];
    #pragma unroll
    for (int jj = 0; jj < 8; ++jj) {
        int j = jj * 256 + tid;
        float s = 0.f;
        #pragma unroll
        for (int d = 0; d < 10; ++d) s += q[d] * kb[(size_t)d * Tt + j];
        e[jj] = s;
    }
    float m = e[0];
    #pragma unroll
    for (int jj = 1; jj < 8; ++jj) m = fmaxf(m, e[jj]);
    #pragma unroll
    for (int off = 32; off > 0; off >>= 1) m = fmaxf(m, __shfl_xor(m, off));
    if (lane == 0) wmax[wid] = m;
    __syncthreads();
    float M = fmaxf(fmaxf(wmax[0], wmax[1]), fmaxf(wmax[2], wmax[3]));
    float sum = 0.f;
    #pragma unroll
    for (int jj = 0; jj < 8; ++jj) { e[jj] = __expf(e[jj] - M); sum += e[jj]; }
    #pragma unroll
    for (int off = 32; off > 0; off >>= 1) sum += __shfl_xor(sum, off);
    if (lane == 0) wsum[wid] = sum;
    __syncthreads();
    float inv = 1.f / (wsum[0] + wsum[1] + wsum[2] + wsum[3]);
    ushort* arow = A + (size_t)bi * Tt;
    #pragma unroll
    for (int jj = 0; jj < 8; ++jj) arow[jj * 256 + tid] = f2bf(e[jj] * inv);
}

// ---------------------------------------------------------------------------
// K5: fused PV + channel conv.  LDS union: {As,Bs} (16KB, stage 1) / Yt (32KB, stage 2)
// Block owns: fixed f, i-tile of 128, batch b.  Rows n = c'*64+f, c' in [0,128).
//  Stage 1 (PV):    Ytile[c'][i] = sum_j Xb[b][c'*64+f][j] * Ab[b][i0+i][j]   (MFMA, K=2048)
//  transpose:       Yt[i][c'] in LDS (bf16, byte ^= (i&7)<<4 swizzle)
//  Stage 2 (conv):  out[b][c*64+f][i0+i] = bv[c] + sum_c' Wvb[c][c'] * Yt[i][c']  (MFMA, K=128)
// grid (64 f, 16 i-tiles, 4 b) x 256
// ---------------------------------------------------------------------------
__global__ __launch_bounds__(256) void k_pv_conv(const ushort* __restrict__ Xb,
                                                 const ushort* __restrict__ Ab,
                                                 const ushort* __restrict__ Wvb,
                                                 const float* __restrict__ bv,
                                                 float* __restrict__ out) {
    __shared__ ushort smem[128 * 128];       // 32 KB
    ushort* As = smem;                        // 4096 ushorts (stage 1)
    ushort* Bs = smem + 4096;                 // 4096 ushorts (stage 1)
    ushort* Yt = smem;                        // full 32 KB   (stage 2)
    int f = blockIdx.x, ib = blockIdx.y, b = blockIdx.z;
    const ushort* xb = Xb + (size_t)b * CF * Tt + (size_t)f * Tt;   // c' row stride 64*Tt
    const ushort* ab = Ab + (size_t)b * Tt * Tt + (size_t)ib * 128 * Tt;
    int tid = threadIdx.x;
    int w = tid >> 6, l = tid & 63;
    int wr = w >> 1, wc = w & 1;

    // staging: wave w stages c'-rows [w*32, w*32+32) of X and i-rows of A
    int srow = w * 32 + (l >> 2);
    int scol = (l & 3) * 8;
    const ushort* xs0 = xb + (size_t)srow * 64 * Tt + scol;
    const ushort* xs1 = xs0 + (size_t)16 * 64 * Tt;
    const ushort* as0 = ab + (size_t)srow * Tt + scol;
    const ushort* as1 = as0 + (size_t)16 * Tt;
    ushort* ldsA0 = As + w * 1024;
    ushort* ldsA1 = As + w * 1024 + 512;
    ushort* ldsB0 = Bs + w * 1024;
    ushort* ldsB1 = Bs + w * 1024 + 512;

    f32x4 acc[4][4];
    #pragma unroll
    for (int m = 0; m < 4; ++m)
        #pragma unroll
        for (int n = 0; n < 4; ++n) acc[m][n] = (f32x4){0.f, 0.f, 0.f, 0.f};

    int frow = (l & 15);
    int koff = (l >> 4) * 8;

    for (int k0 = 0; k0 < Tt; k0 += 32) {
        gload_lds16(xs0 + k0, ldsA0);
        gload_lds16(xs1 + k0, ldsA1);
        gload_lds16(as0 + k0, ldsB0);
        gload_lds16(as1 + k0, ldsB1);
        __syncthreads();
        bf16x8 afr[4], bfr[4];
        #pragma unroll
        for (int m = 0; m < 4; ++m)
            afr[m] = *(const bf16x8*)&As[(wr * 64 + m * 16 + frow) * 32 + koff];
        #pragma unroll
        for (int n = 0; n < 4; ++n)
            bfr[n] = *(const bf16x8*)&Bs[(wc * 64 + n * 16 + frow) * 32 + koff];
        #pragma unroll
        for (int m = 0; m < 4; ++m)
            #pragma unroll
            for (int n = 0; n < 4; ++n)
                acc[m][n] = __builtin_amdgcn_mfma_f32_16x16x32_bf16(afr[m], bfr[n], acc[m][n], 0, 0, 0);
        __syncthreads();
    }

    // ---- transpose acc -> Yt[i][c'] (bf16, swizzled); As/Bs dead, smem reused ----
    // acc[m][n][r] = Y[c' = wr*64 + m*16 + (l>>4)*4 + r][i = wc*64 + n*16 + (l&15)]
    int rbase = wr * 64 + ((l >> 4) << 2);
    #pragma unroll
    for (int n = 0; n < 4; ++n) {
        int i = wc * 64 + n * 16 + (l & 15);
        int swz = (i & 7) << 4;
        #pragma unroll
        for (int m = 0; m < 4; ++m) {
            int cp = rbase + m * 16;
            ushort4 v;
            v.x = f2bf(acc[m][n][0]); v.y = f2bf(acc[m][n][1]);
            v.z = f2bf(acc[m][n][2]); v.w = f2bf(acc[m][n][3]);
            *(ushort4*)((char*)Yt + (((i << 8) + (cp << 1)) ^ swz)) = v;
        }
    }
    __syncthreads();

    // ---- stage 2: Out[c][i] = sum_c' Wvb[c][c'] * Yt[i][c'], K=128 ----
    f32x4 acc2[4][4];
    #pragma unroll
    for (int m = 0; m < 4; ++m)
        #pragma unroll
        for (int n = 0; n < 4; ++n) acc2[m][n] = (f32x4){0.f, 0.f, 0.f, 0.f};
    #pragma unroll
    for (int ks = 0; ks < 4; ++ks) {
        int kofs = ks * 32 + koff;
        bf16x8 afr[4], bfr[4];
        #pragma unroll
        for (int m = 0; m < 4; ++m) {
            int c = wr * 64 + m * 16 + frow;
            afr[m] = *(const bf16x8*)&Wvb[c * 128 + kofs];
        }
        #pragma unroll
        for (int n = 0; n < 4; ++n) {
            int i = wc * 64 + n * 16 + frow;
            bfr[n] = *(const bf16x8*)((const char*)Yt + (((i << 8) + (kofs << 1)) ^ ((i & 7) << 4)));
        }
        #pragma unroll
        for (int m = 0; m < 4; ++m)
            #pragma unroll
            for (int n = 0; n < 4; ++n)
                acc2[m][n] = __builtin_amdgcn_mfma_f32_16x16x32_bf16(afr[m], bfr[n], acc2[m][n], 0, 0, 0);
    }

    // ---- bias + write d_out ----
    float* ob = out + (size_t)b * CF * Tt + (size_t)f * Tt + (size_t)ib * 128;
    #pragma unroll
    for (int m = 0; m < 4; ++m) {
        #pragma unroll
        for (int r = 0; r < 4; ++r) {
            int c = wr * 64 + m * 16 + ((l >> 4) << 2) + r;
            float bvv = bv[c];
            #pragma unroll
            for (int n = 0; n < 4; ++n) {
                int col = wc * 64 + n * 16 + (l & 15);
                ob[(size_t)c * 64 * Tt + col] = acc2[m][n][r] + bvv;
            }
        }
    }
}

// ---------------------------------------------------------------------------
extern "C" void kernel_launch(void* const* d_in, const int* in_sizes, int n_in,
                              void* d_out, int out_size, void* d_ws, size_t ws_size,
                              hipStream_t stream) {
    const float* x       = (const float*)d_in[0];
    const float* Wq_conv = (const float*)d_in[1];
    const float* bq_conv = (const float*)d_in[2];
    const float* Wq_lin  = (const float*)d_in[3];
    const float* bq_lin  = (const float*)d_in[4];
    const float* Wk_conv = (const float*)d_in[5];
    const float* bk_conv = (const float*)d_in[6];
    const float* Wk_lin  = (const float*)d_in[7];
    const float* bk_lin  = (const float*)d_in[8];
    const float* Wv      = (const float*)d_in[9];
    const float* bv      = (const float*)d_in[10];
    float* out = (float*)d_out;

    float* ws   = (float*)d_ws;
    float* weff = ws;                         // 163840
    float* cqk  = weff + 163840;              // 32
    float* part = cqk + 32;                   // 5242880
    float* Qb   = part + 5242880;             // 81920
    float* Ktb  = Qb + 81920;                 // 81920
    float* Abf_f = Ktb + 81920;               // 8388608 floats = 16.7M bf16
    float* Xbf_f = Abf_f + 8388608;           // 33554432 floats = 67.1M bf16
    float* Wvb_f = Xbf_f + 33554432;          // 8192 floats = 16384 bf16
    ushort* Abf = (ushort*)Abf_f;
    ushort* Xbf = (ushort*)Xbf_f;
    ushort* Wvb = (ushort*)Wvb_f;

    k_prep <<<705, 256, 0, stream>>>(Wq_lin, Wq_conv, Wk_lin, Wk_conv,
                                     bq_conv, bq_lin, bk_conv, bk_lin, Wv,
                                     weff, cqk, Wvb);
    k_qk   <<<512, 256, 0, stream>>>(x, weff, part, Xbf);
    k_qkred<<<dim3(32, 20), 256, 0, stream>>>(part, cqk, Qb, Ktb);
    k_att  <<<8192, 256, 0, stream>>>(Qb, Ktb, Abf);
    k_pv_conv<<<dim3(64, 16, 4), 256, 0, stream>>>(Xbf, Abf, Wvb, bv, out);
}

// Round 5
// 545.541 us; speedup vs baseline: 8.1418x; 1.0953x over previous
//
#include <hip/hip_runtime.h>
#include <hip/hip_bf16.h>

#define Bq 4
#define Cc 128
#define Ff 64
#define Tt 2048
#define CF 8192     // C*F
#define NCHUNK 32   // cf chunks for QK pass
#define CHUNK 256   // cf per chunk

typedef __attribute__((ext_vector_type(4))) float f32x4;
typedef __attribute__((ext_vector_type(8))) short bf16x8;

__device__ inline ushort f2bf(float f) {
    __hip_bfloat16 h = __float2bfloat16(f);   // round-to-nearest
    return *reinterpret_cast<ushort*>(&h);
}

__device__ inline void gload_lds16(const void* g, void* l) {
    __builtin_amdgcn_global_load_lds(
        (const __attribute__((address_space(1))) void*)g,
        (__attribute__((address_space(3))) void*)l, 16, 0, 0);
}

// ---------------------------------------------------------------------------
// K1: merged prep.
//  blocks [0,640):   weff[cf][d]  (d<10: q, d>=10: k), cf = c*64+f
//  blocks [640,704): Wv -> bf16
//  block  704:       cqk constants
// ---------------------------------------------------------------------------
__global__ void k_prep(const float* __restrict__ Wq_lin, const float* __restrict__ Wq_conv,
                       const float* __restrict__ Wk_lin, const float* __restrict__ Wk_conv,
                       const float* __restrict__ bq_conv, const float* __restrict__ bq_lin,
                       const float* __restrict__ bk_conv, const float* __restrict__ bk_lin,
                       const float* __restrict__ Wv,
                       float* __restrict__ weff, float* __restrict__ cqk,
                       ushort* __restrict__ Wvb) {
    int blk = blockIdx.x;
    if (blk < 640) {
        int gid = blk * 256 + threadIdx.x;
        if (gid >= CF * 20) return;
        int cf = gid / 20, d = gid % 20;
        int c = cf >> 6, f = cf & 63;
        float s = 0.f;
        if (d < 10) {
            #pragma unroll
            for (int o = 0; o < 4; ++o) s += Wq_lin[d * 256 + o * 64 + f] * Wq_conv[o * 128 + c];
        } else {
            int dd = d - 10;
            #pragma unroll
            for (int o = 0; o < 4; ++o) s += Wk_lin[dd * 256 + o * 64 + f] * Wk_conv[o * 128 + c];
        }
        weff[cf * 20 + d] = s;
    } else if (blk < 704) {
        int i = (blk - 640) * 256 + threadIdx.x;
        if (i < 16384) Wvb[i] = f2bf(Wv[i]);
    } else {
        int d = threadIdx.x;
        if (d >= 20) return;
        float s;
        if (d < 10) {
            s = bq_lin[d];
            for (int o = 0; o < 4; ++o) {
                float bb = bq_conv[o];
                for (int f = 0; f < 64; ++f) s += Wq_lin[d * 256 + o * 64 + f] * bb;
            }
        } else {
            int dd = d - 10;
            s = bk_lin[dd];
            for (int o = 0; o < 4; ++o) {
                float bb = bk_conv[o];
                for (int f = 0; f < 64; ++f) s += Wk_lin[dd * 256 + o * 64 + f] * bb;
            }
        }
        cqk[d] = s;
    }
}

// ---------------------------------------------------------------------------
// K2: QK partials + x->bf16 side-write.
// partial[b][ch][d][t] = sum_{cf in chunk} x[b][cf][t]*Weff[cf][d]
// ---------------------------------------------------------------------------
__global__ __launch_bounds__(256) void k_qk(const float* __restrict__ x,
                                            const float* __restrict__ weff,
                                            float* __restrict__ partial,
                                            ushort* __restrict__ xbf) {
    int blk = blockIdx.x;
    int tt = blk & 3;
    int ch = (blk >> 2) & 31;
    int b  = blk >> 7;
    int t = tt * 512 + threadIdx.x * 2;
    const float* xb = x + (size_t)b * CF * Tt;
    ushort* xob = xbf + (size_t)b * CF * Tt;
    float acc[20][2];
    #pragma unroll
    for (int d = 0; d < 20; ++d) { acc[d][0] = 0.f; acc[d][1] = 0.f; }
    int cf0 = ch * CHUNK;
    for (int cf = cf0; cf < cf0 + CHUNK; ++cf) {
        float2 xv = *(const float2*)(xb + (size_t)cf * Tt + t);
        *(ushort2*)(xob + (size_t)cf * Tt + t) = make_ushort2(f2bf(xv.x), f2bf(xv.y));
        const float* w = weff + cf * 20;   // uniform address -> s_loads
        #pragma unroll
        for (int d = 0; d < 20; ++d) {
            float wv = w[d];
            acc[d][0] += wv * xv.x;
            acc[d][1] += wv * xv.y;
        }
    }
    float* pb = partial + (size_t)(b * NCHUNK + ch) * 20 * Tt;
    #pragma unroll
    for (int d = 0; d < 20; ++d)
        *(float2*)(pb + (size_t)d * Tt + t) = make_float2(acc[d][0], acc[d][1]);
}

// K3: reduce partials + const -> Q[b][t][10], Kt[b][10][t].  grid (32,20) x 256
__global__ void k_qkred(const float* __restrict__ partial, const float* __restrict__ cqk,
                        float* __restrict__ Q, float* __restrict__ Kt) {
    int t = blockIdx.x * 256 + threadIdx.x;  // 0..8191
    int d = blockIdx.y;                      // 0..19
    int b = t >> 11, tl = t & 2047;
    float s = cqk[d];
    #pragma unroll 4
    for (int ch = 0; ch < NCHUNK; ++ch)
        s += partial[((size_t)(b * NCHUNK + ch) * 20 + d) * Tt + tl];
    if (d < 10) Q[(size_t)(b * 2048 + tl) * 10 + d] = s;
    else        Kt[((size_t)b * 10 + (d - 10)) * Tt + tl] = s;
}

// ---------------------------------------------------------------------------
// K4: energy + softmax -> A_bf16[b][i][j].  block per (b,i): 8192 blocks x 256
// ---------------------------------------------------------------------------
__global__ __launch_bounds__(256) void k_att(const float* __restrict__ Q,
                                             const float* __restrict__ Kt,
                                             ushort* __restrict__ A) {
    int bi = blockIdx.x;
    int b = bi >> 11;
    __shared__ float qs[10];
    __shared__ float wmax[4];
    __shared__ float wsum[4];
    int tid = threadIdx.x;
    int lane = tid & 63, wid = tid >> 6;
    if (tid < 10) qs[tid] = Q[(size_t)bi * 10 + tid];
    __syncthreads();
    float q[10];
    #pragma unroll
    for (int d = 0; d < 10; ++d) q[d] = qs[d];
    const float* kb = Kt + (size_t)b * 10 * Tt;
    float e[8];
    #pragma unroll
    for (int jj = 0; jj < 8; ++jj) {
        int j = jj * 256 + tid;
        float s = 0.f;
        #pragma unroll
        for (int d = 0; d < 10; ++d) s += q[d] * kb[(size_t)d * Tt + j];
        e[jj] = s;
    }
    float m = e[0];
    #pragma unroll
    for (int jj = 1; jj < 8; ++jj) m = fmaxf(m, e[jj]);
    #pragma unroll
    for (int off = 32; off > 0; off >>= 1) m = fmaxf(m, __shfl_xor(m, off));
    if (lane == 0) wmax[wid] = m;
    __syncthreads();
    float M = fmaxf(fmaxf(wmax[0], wmax[1]), fmaxf(wmax[2], wmax[3]));
    float sum = 0.f;
    #pragma unroll
    for (int jj = 0; jj < 8; ++jj) { e[jj] = __expf(e[jj] - M); sum += e[jj]; }
    #pragma unroll
    for (int off = 32; off > 0; off >>= 1) sum += __shfl_xor(sum, off);
    if (lane == 0) wsum[wid] = sum;
    __syncthreads();
    float inv = 1.f / (wsum[0] + wsum[1] + wsum[2] + wsum[3]);
    ushort* arow = A + (size_t)bi * Tt;
    #pragma unroll
    for (int jj = 0; jj < 8; ++jj) arow[jj * 256 + tid] = f2bf(e[jj] * inv);
}

// ---------------------------------------------------------------------------
// K5: fused PV + channel conv — 2-phase double-buffered K-loop (T3-minimal).
// LDS: 2 buffers x (As 8KB | Bs 8KB) = 32KB; Yt (32KB) overlays after the loop.
//  Stage 1 (PV):    Ytile[c'][i] = sum_j Xb[b][c'*64+f][j] * Ab[b][i0+i][j]
//  transpose:       Yt[i][c'] bf16, byte ^= (i&7)<<4 swizzle
//  Stage 2 (conv):  out[b][c*64+f][i0+i] = bv[c] + sum_c' Wvb[c][c'] * Yt[i][c']
// grid (64 f, 16 i-tiles, 4 b) x 256
// ---------------------------------------------------------------------------
__global__ __launch_bounds__(256) void k_pv_conv(const ushort* __restrict__ Xb,
                                                 const ushort* __restrict__ Ab,
                                                 const ushort* __restrict__ Wvb,
                                                 const float* __restrict__ bv,
                                                 float* __restrict__ out) {
    __shared__ ushort smem[2][8192];          // [buf][ As(4096) | Bs(4096) ]
    ushort* Yt = &smem[0][0];                 // stage-2 overlay, 32 KB
    int f = blockIdx.x, ib = blockIdx.y, b = blockIdx.z;
    const ushort* xb = Xb + (size_t)b * CF * Tt + (size_t)f * Tt;   // c' row stride 64*Tt
    const ushort* ab = Ab + (size_t)b * Tt * Tt + (size_t)ib * 128 * Tt;
    int tid = threadIdx.x;
    int w = tid >> 6, l = tid & 63;
    int wr = w >> 1, wc = w & 1;

    // staging: wave w stages c'-rows [w*32, w*32+32) of X and i-rows of A
    int srow = w * 32 + (l >> 2);
    int scol = (l & 3) * 8;
    const ushort* xs0 = xb + (size_t)srow * 64 * Tt + scol;
    const ushort* xs1 = xs0 + (size_t)16 * 64 * Tt;
    const ushort* as0 = ab + (size_t)srow * Tt + scol;
    const ushort* as1 = as0 + (size_t)16 * Tt;
    int ldsOffA = w * 1024;                   // within As half
    int ldsOffB = 4096 + w * 1024;            // within Bs half

    f32x4 acc[4][4];
    #pragma unroll
    for (int m = 0; m < 4; ++m)
        #pragma unroll
        for (int n = 0; n < 4; ++n) acc[m][n] = (f32x4){0.f, 0.f, 0.f, 0.f};

    int frow = (l & 15);
    int koff = (l >> 4) * 8;

    // prologue: stage tile 0 into buf 0
    gload_lds16(xs0, &smem[0][ldsOffA]);
    gload_lds16(xs1, &smem[0][ldsOffA + 512]);
    gload_lds16(as0, &smem[0][ldsOffB]);
    gload_lds16(as1, &smem[0][ldsOffB + 512]);
    __syncthreads();

    for (int t = 0; t < 64; ++t) {
        int cur = t & 1;
        if (t < 63) {
            int k1 = (t + 1) * 32;
            int nxt = cur ^ 1;
            gload_lds16(xs0 + k1, &smem[nxt][ldsOffA]);
            gload_lds16(xs1 + k1, &smem[nxt][ldsOffA + 512]);
            gload_lds16(as0 + k1, &smem[nxt][ldsOffB]);
            gload_lds16(as1 + k1, &smem[nxt][ldsOffB + 512]);
        }
        const ushort* As = &smem[cur][0];
        const ushort* Bs = &smem[cur][4096];
        bf16x8 afr[4], bfr[4];
        #pragma unroll
        for (int m = 0; m < 4; ++m)
            afr[m] = *(const bf16x8*)&As[(wr * 64 + m * 16 + frow) * 32 + koff];
        #pragma unroll
        for (int n = 0; n < 4; ++n)
            bfr[n] = *(const bf16x8*)&Bs[(wc * 64 + n * 16 + frow) * 32 + koff];
        #pragma unroll
        for (int m = 0; m < 4; ++m)
            #pragma unroll
            for (int n = 0; n < 4; ++n)
                acc[m][n] = __builtin_amdgcn_mfma_f32_16x16x32_bf16(afr[m], bfr[n], acc[m][n], 0, 0, 0);
        // single barrier per k-step: (a) all waves done reading smem[cur]
        // (lgkmcnt drained) so it may be overwritten next iter; (b) drains
        // vmcnt(0) => the prefetch issued ABOVE (latency overlapped by the
        // ds_read+MFMA just executed) has landed for the next iter.
        __syncthreads();
    }

    // ---- transpose acc -> Yt[i][c'] (bf16, swizzled); buffers dead, smem reused ----
    // acc[m][n][r] = Y[c' = wr*64 + m*16 + (l>>4)*4 + r][i = wc*64 + n*16 + (l&15)]
    int rbase = wr * 64 + ((l >> 4) << 2);
    #pragma unroll
    for (int n = 0; n < 4; ++n) {
        int i = wc * 64 + n * 16 + (l & 15);
        int swz = (i & 7) << 4;
        #pragma unroll
        for (int m = 0; m < 4; ++m) {
            int cp = rbase + m * 16;
            ushort4 v;
            v.x = f2bf(acc[m][n][0]); v.y = f2bf(acc[m][n][1]);
            v.z = f2bf(acc[m][n][2]); v.w = f2bf(acc[m][n][3]);
            *(ushort4*)((char*)Yt + (((i << 8) + (cp << 1)) ^ swz)) = v;
        }
    }
    __syncthreads();

    // ---- stage 2: Out[c][i] = sum_c' Wvb[c][c'] * Yt[i][c'], K=128 ----
    f32x4 acc2[4][4];
    #pragma unroll
    for (int m = 0; m < 4; ++m)
        #pragma unroll
        for (int n = 0; n < 4; ++n) acc2[m][n] = (f32x4){0.f, 0.f, 0.f, 0.f};
    #pragma unroll
    for (int ks = 0; ks < 4; ++ks) {
        int kofs = ks * 32 + koff;
        bf16x8 afr[4], bfr[4];
        #pragma unroll
        for (int m = 0; m < 4; ++m) {
            int c = wr * 64 + m * 16 + frow;
            afr[m] = *(const bf16x8*)&Wvb[c * 128 + kofs];
        }
        #pragma unroll
        for (int n = 0; n < 4; ++n) {
            int i = wc * 64 + n * 16 + frow;
            bfr[n] = *(const bf16x8*)((const char*)Yt + (((i << 8) + (kofs << 1)) ^ ((i & 7) << 4)));
        }
        #pragma unroll
        for (int m = 0; m < 4; ++m)
            #pragma unroll
            for (int n = 0; n < 4; ++n)
                acc2[m][n] = __builtin_amdgcn_mfma_f32_16x16x32_bf16(afr[m], bfr[n], acc2[m][n], 0, 0, 0);
    }

    // ---- bias + write d_out ----
    float* ob = out + (size_t)b * CF * Tt + (size_t)f * Tt + (size_t)ib * 128;
    #pragma unroll
    for (int m = 0; m < 4; ++m) {
        #pragma unroll
        for (int r = 0; r < 4; ++r) {
            int c = wr * 64 + m * 16 + ((l >> 4) << 2) + r;
            float bvv = bv[c];
            #pragma unroll
            for (int n = 0; n < 4; ++n) {
                int col = wc * 64 + n * 16 + (l & 15);
                ob[(size_t)c * 64 * Tt + col] = acc2[m][n][r] + bvv;
            }
        }
    }
}

// ---------------------------------------------------------------------------
extern "C" void kernel_launch(void* const* d_in, const int* in_sizes, int n_in,
                              void* d_out, int out_size, void* d_ws, size_t ws_size,
                              hipStream_t stream) {
    const float* x       = (const float*)d_in[0];
    const float* Wq_conv = (const float*)d_in[1];
    const float* bq_conv = (const float*)d_in[2];
    const float* Wq_lin  = (const float*)d_in[3];
    const float* bq_lin  = (const float*)d_in[4];
    const float* Wk_conv = (const float*)d_in[5];
    const float* bk_conv = (const float*)d_in[6];
    const float* Wk_lin  = (const float*)d_in[7];
    const float* bk_lin  = (const float*)d_in[8];
    const float* Wv      = (const float*)d_in[9];
    const float* bv      = (const float*)d_in[10];
    float* out = (float*)d_out;

    float* ws   = (float*)d_ws;
    float* weff = ws;                         // 163840
    float* cqk  = weff + 163840;              // 32
    float* part = cqk + 32;                   // 5242880
    float* Qb   = part + 5242880;             // 81920
    float* Ktb  = Qb + 81920;                 // 81920
    float* Abf_f = Ktb + 81920;               // 8388608 floats = 16.7M bf16
    float* Xbf_f = Abf_f + 8388608;           // 33554432 floats = 67.1M bf16
    float* Wvb_f = Xbf_f + 33554432;          // 8192 floats = 16384 bf16
    ushort* Abf = (ushort*)Abf_f;
    ushort* Xbf = (ushort*)Xbf_f;
    ushort* Wvb = (ushort*)Wvb_f;

    k_prep <<<705, 256, 0, stream>>>(Wq_lin, Wq_conv, Wk_lin, Wk_conv,
                                     bq_conv, bq_lin, bk_conv, bk_lin, Wv,
                                     weff, cqk, Wvb);
    k_qk   <<<512, 256, 0, stream>>>(x, weff, part, Xbf);
    k_qkred<<<dim3(32, 20), 256, 0, stream>>>(part, cqk, Qb, Ktb);
    k_att  <<<8192, 256, 0, stream>>>(Qb, Ktb, Abf);
    k_pv_conv<<<dim3(64, 16, 4), 256, 0, stream>>>(Xbf, Abf, Wvb, bv, out);
}

// Round 6
// 527.609 us; speedup vs baseline: 8.4185x; 1.0340x over previous
//
#include <hip/hip_runtime.h>
#include <hip/hip_bf16.h>

#define Bq 4
#define Cc 128
#define Ff 64
#define Tt 2048
#define CF 8192     // C*F
#define NCHUNK 32   // cf chunks for QK pass
#define CHUNK 256   // cf per chunk

typedef __attribute__((ext_vector_type(4))) float f32x4;
typedef __attribute__((ext_vector_type(8))) short bf16x8;

__device__ inline ushort f2bf(float f) {
    __hip_bfloat16 h = __float2bfloat16(f);   // round-to-nearest
    return *reinterpret_cast<ushort*>(&h);
}

__device__ inline void gload_lds16(const void* g, void* l) {
    __builtin_amdgcn_global_load_lds(
        (const __attribute__((address_space(1))) void*)g,
        (__attribute__((address_space(3))) void*)l, 16, 0, 0);
}

// ---------------------------------------------------------------------------
// K1: merged prep.
//  blocks [0,640):   weff[cf][d]  (d<10: q, d>=10: k), cf = c*64+f
//  blocks [640,704): Wv -> bf16
//  block  704:       cqk constants
// ---------------------------------------------------------------------------
__global__ void k_prep(const float* __restrict__ Wq_lin, const float* __restrict__ Wq_conv,
                       const float* __restrict__ Wk_lin, const float* __restrict__ Wk_conv,
                       const float* __restrict__ bq_conv, const float* __restrict__ bq_lin,
                       const float* __restrict__ bk_conv, const float* __restrict__ bk_lin,
                       const float* __restrict__ Wv,
                       float* __restrict__ weff, float* __restrict__ cqk,
                       ushort* __restrict__ Wvb) {
    int blk = blockIdx.x;
    if (blk < 640) {
        int gid = blk * 256 + threadIdx.x;
        if (gid >= CF * 20) return;
        int cf = gid / 20, d = gid % 20;
        int c = cf >> 6, f = cf & 63;
        float s = 0.f;
        if (d < 10) {
            #pragma unroll
            for (int o = 0; o < 4; ++o) s += Wq_lin[d * 256 + o * 64 + f] * Wq_conv[o * 128 + c];
        } else {
            int dd = d - 10;
            #pragma unroll
            for (int o = 0; o < 4; ++o) s += Wk_lin[dd * 256 + o * 64 + f] * Wk_conv[o * 128 + c];
        }
        weff[cf * 20 + d] = s;
    } else if (blk < 704) {
        int i = (blk - 640) * 256 + threadIdx.x;
        if (i < 16384) Wvb[i] = f2bf(Wv[i]);
    } else {
        int d = threadIdx.x;
        if (d >= 20) return;
        float s;
        if (d < 10) {
            s = bq_lin[d];
            for (int o = 0; o < 4; ++o) {
                float bb = bq_conv[o];
                for (int f = 0; f < 64; ++f) s += Wq_lin[d * 256 + o * 64 + f] * bb;
            }
        } else {
            int dd = d - 10;
            s = bk_lin[dd];
            for (int o = 0; o < 4; ++o) {
                float bb = bk_conv[o];
                for (int f = 0; f < 64; ++f) s += Wk_lin[dd * 256 + o * 64 + f] * bb;
            }
        }
        cqk[d] = s;
    }
}

// ---------------------------------------------------------------------------
// K2: QK partials + x->bf16 side-write.
// ---------------------------------------------------------------------------
__global__ __launch_bounds__(256) void k_qk(const float* __restrict__ x,
                                            const float* __restrict__ weff,
                                            float* __restrict__ partial,
                                            ushort* __restrict__ xbf) {
    int blk = blockIdx.x;
    int tt = blk & 3;
    int ch = (blk >> 2) & 31;
    int b  = blk >> 7;
    int t = tt * 512 + threadIdx.x * 2;
    const float* xb = x + (size_t)b * CF * Tt;
    ushort* xob = xbf + (size_t)b * CF * Tt;
    float acc[20][2];
    #pragma unroll
    for (int d = 0; d < 20; ++d) { acc[d][0] = 0.f; acc[d][1] = 0.f; }
    int cf0 = ch * CHUNK;
    for (int cf = cf0; cf < cf0 + CHUNK; ++cf) {
        float2 xv = *(const float2*)(xb + (size_t)cf * Tt + t);
        *(ushort2*)(xob + (size_t)cf * Tt + t) = make_ushort2(f2bf(xv.x), f2bf(xv.y));
        const float* w = weff + cf * 20;   // uniform address -> s_loads
        #pragma unroll
        for (int d = 0; d < 20; ++d) {
            float wv = w[d];
            acc[d][0] += wv * xv.x;
            acc[d][1] += wv * xv.y;
        }
    }
    float* pb = partial + (size_t)(b * NCHUNK + ch) * 20 * Tt;
    #pragma unroll
    for (int d = 0; d < 20; ++d)
        *(float2*)(pb + (size_t)d * Tt + t) = make_float2(acc[d][0], acc[d][1]);
}

// K3: reduce partials + const -> Q[b][t][10], Kt[b][10][t].  grid (32,20) x 256
__global__ void k_qkred(const float* __restrict__ partial, const float* __restrict__ cqk,
                        float* __restrict__ Q, float* __restrict__ Kt) {
    int t = blockIdx.x * 256 + threadIdx.x;  // 0..8191
    int d = blockIdx.y;                      // 0..19
    int b = t >> 11, tl = t & 2047;
    float s = cqk[d];
    #pragma unroll 4
    for (int ch = 0; ch < NCHUNK; ++ch)
        s += partial[((size_t)(b * NCHUNK + ch) * 20 + d) * Tt + tl];
    if (d < 10) Q[(size_t)(b * 2048 + tl) * 10 + d] = s;
    else        Kt[((size_t)b * 10 + (d - 10)) * Tt + tl] = s;
}

// ---------------------------------------------------------------------------
// K4: energy + softmax -> A_bf16[b][i][j].  block per (b,i): 8192 blocks x 256
// ---------------------------------------------------------------------------
__global__ __launch_bounds__(256) void k_att(const float* __restrict__ Q,
                                             const float* __restrict__ Kt,
                                             ushort* __restrict__ A) {
    int bi = blockIdx.x;
    int b = bi >> 11;
    __shared__ float qs[10];
    __shared__ float wmax[4];
    __shared__ float wsum[4];
    int tid = threadIdx.x;
    int lane = tid & 63, wid = tid >> 6;
    if (tid < 10) qs[tid] = Q[(size_t)bi * 10 + tid];
    __syncthreads();
    float q[10];
    #pragma unroll
    for (int d = 0; d < 10; ++d) q[d] = qs[d];
    const float* kb = Kt + (size_t)b * 10 * Tt;
    float e[8];
    #pragma unroll
    for (int jj = 0; jj < 8; ++jj) {
        int j = jj * 256 + tid;
        float s = 0.f;
        #pragma unroll
        for (int d = 0; d < 10; ++d) s += q[d] * kb[(size_t)d * Tt + j];
        e[jj] = s;
    }
    float m = e[0];
    #pragma unroll
    for (int jj = 1; jj < 8; ++jj) m = fmaxf(m, e[jj]);
    #pragma unroll
    for (int off = 32; off > 0; off >>= 1) m = fmaxf(m, __shfl_xor(m, off));
    if (lane == 0) wmax[wid] = m;
    __syncthreads();
    float M = fmaxf(fmaxf(wmax[0], wmax[1]), fmaxf(wmax[2], wmax[3]));
    float sum = 0.f;
    #pragma unroll
    for (int jj = 0; jj < 8; ++jj) { e[jj] = __expf(e[jj] - M); sum += e[jj]; }
    #pragma unroll
    for (int off = 32; off > 0; off >>= 1) sum += __shfl_xor(sum, off);
    if (lane == 0) wsum[wid] = sum;
    __syncthreads();
    float inv = 1.f / (wsum[0] + wsum[1] + wsum[2] + wsum[3]);
    ushort* arow = A + (size_t)bi * Tt;
    #pragma unroll
    for (int jj = 0; jj < 8; ++jj) arow[jj * 256 + tid] = f2bf(e[jj] * inv);
}

// ---------------------------------------------------------------------------
// K5: fused PV + channel conv — counted-vmcnt 3-deep pipeline (T3+T4) with
// bank-conflict-free LDS via source-pre-swizzle (T2, rule #21).
//
// LDS tile layout (per buffer, 16KB): As rows 0..127 x 32 bf16, then Bs same.
// Read swizzle: byte addr = (row*64 + chunk*16) ^ ((row&7)<<4)
// gload_lds writes linearly (wave base + lane*16B), so the global SOURCE is
// permuted per lane:  lane l stages (row_s, c_s) with
//   lr=l>>2; row_s=(lr&14)|((lr^(lr>>2))&1); c_s=((l1^l3)<<1)|(l0^l2^l4)
// (bijective; hand-verified: f(row_s,c_s)=l*16 for l=5,9,63.)
//
// Pipeline per k-step t: [vmcnt(4)] [s_barrier] [STAGE(t+2)] [ds_read+MFMA(t)]
// No vmcnt(0) in the loop. Buffer (t+2)%3 was read at t-1, whose reads all
// returned before the iter-t barrier; tile t's loads are covered by each
// wave's own vmcnt(4) + the barrier.
// grid (64 f, 16 i-tiles, 4 b) x 256
// ---------------------------------------------------------------------------
__global__ __launch_bounds__(256) void k_pv_conv(const ushort* __restrict__ Xb,
                                                 const ushort* __restrict__ Ab,
                                                 const ushort* __restrict__ Wvb,
                                                 const float* __restrict__ bv,
                                                 float* __restrict__ out) {
    __shared__ ushort smem[3][8192];          // 3 x (As 8KB | Bs 8KB) = 48KB
    ushort* Yt = &smem[0][0];                 // stage-2 overlay, 32 KB
    int f = blockIdx.x, ib = blockIdx.y, b = blockIdx.z;
    const ushort* xb = Xb + (size_t)b * CF * Tt + (size_t)f * Tt;   // c' row stride 64*Tt
    const ushort* ab = Ab + (size_t)b * Tt * Tt + (size_t)ib * 128 * Tt;
    int tid = threadIdx.x;
    int w = tid >> 6, l = tid & 63;
    int wr = w >> 1, wc = w & 1;

    // ---- pre-swizzled staging source coords (T2 inverse permutation) ----
    int lr = l >> 2;
    int row_s = (lr & 14) | ((lr ^ (lr >> 2)) & 1);
    int c_s = ((((l >> 1) ^ (l >> 3)) & 1) << 1) | ((l ^ (l >> 2) ^ (l >> 4)) & 1);
    int srow = w * 32 + row_s;
    int scol = c_s * 8;
    const ushort* xs0 = xb + (size_t)srow * 64 * Tt + scol;
    const ushort* xs1 = xs0 + (size_t)16 * 64 * Tt;
    const ushort* as0 = ab + (size_t)srow * Tt + scol;
    const ushort* as1 = as0 + (size_t)16 * Tt;
    int ldsA = w * 1024;                      // ushort offset of wave's As segment

#define STAGE(tt, d) do {                                   \
        int kk = (tt) * 32;                                 \
        ushort* bb = &smem[d][0];                           \
        gload_lds16(xs0 + kk, bb + ldsA);                   \
        gload_lds16(xs1 + kk, bb + ldsA + 512);             \
        gload_lds16(as0 + kk, bb + 4096 + ldsA);            \
        gload_lds16(as1 + kk, bb + 4096 + ldsA + 512);      \
    } while (0)

    f32x4 acc[4][4];
    #pragma unroll
    for (int m = 0; m < 4; ++m)
        #pragma unroll
        for (int n = 0; n < 4; ++n) acc[m][n] = (f32x4){0.f, 0.f, 0.f, 0.f};

    int frow = l & 15;
    // thread-constant swizzled fragment byte offset within a 16-row panel:
    // (frow*64 + (l>>4)*16) ^ ((frow&7)<<4)   [< 1024, so panel strides add]
    int rdOff = ((frow << 6) + ((l >> 4) << 4)) ^ ((frow & 7) << 4);

    // prologue: 2 tiles in flight
    STAGE(0, 0);
    STAGE(1, 1);

    int cur = 0;
    for (int t = 0; t < 64; ++t) {
        if (t < 63) asm volatile("s_waitcnt vmcnt(4)" ::: "memory");
        else        asm volatile("s_waitcnt vmcnt(0)" ::: "memory");
        __builtin_amdgcn_s_barrier();
        if (t + 2 < 64) {
            int sb = cur + 2; if (sb >= 3) sb -= 3;
            STAGE(t + 2, sb);
        }
        const char* As8 = (const char*)&smem[cur][0];
        const char* Bs8 = As8 + 8192;
        bf16x8 afr[4], bfr[4];
        #pragma unroll
        for (int m = 0; m < 4; ++m)
            afr[m] = *(const bf16x8*)(As8 + wr * 4096 + m * 1024 + rdOff);
        #pragma unroll
        for (int n = 0; n < 4; ++n)
            bfr[n] = *(const bf16x8*)(Bs8 + wc * 4096 + n * 1024 + rdOff);
        #pragma unroll
        for (int m = 0; m < 4; ++m)
            #pragma unroll
            for (int n = 0; n < 4; ++n)
                acc[m][n] = __builtin_amdgcn_mfma_f32_16x16x32_bf16(afr[m], bfr[n], acc[m][n], 0, 0, 0);
        cur = (cur == 2) ? 0 : cur + 1;
    }
    __syncthreads();   // all MFMAs/reads done before Yt overlays smem[0..1]

    // ---- transpose acc -> Yt[i][c'] (bf16, swizzled) ----
    // acc[m][n][r] = Y[c' = wr*64 + m*16 + (l>>4)*4 + r][i = wc*64 + n*16 + (l&15)]
    int rbase = wr * 64 + ((l >> 4) << 2);
    #pragma unroll
    for (int n = 0; n < 4; ++n) {
        int i = wc * 64 + n * 16 + (l & 15);
        int swz = (i & 7) << 4;
        #pragma unroll
        for (int m = 0; m < 4; ++m) {
            int cp = rbase + m * 16;
            ushort4 v;
            v.x = f2bf(acc[m][n][0]); v.y = f2bf(acc[m][n][1]);
            v.z = f2bf(acc[m][n][2]); v.w = f2bf(acc[m][n][3]);
            *(ushort4*)((char*)Yt + (((i << 8) + (cp << 1)) ^ swz)) = v;
        }
    }
    __syncthreads();

    // ---- stage 2: Out[c][i] = sum_c' Wvb[c][c'] * Yt[i][c'], K=128 ----
    int koff = (l >> 4) * 8;
    f32x4 acc2[4][4];
    #pragma unroll
    for (int m = 0; m < 4; ++m)
        #pragma unroll
        for (int n = 0; n < 4; ++n) acc2[m][n] = (f32x4){0.f, 0.f, 0.f, 0.f};
    #pragma unroll
    for (int ks = 0; ks < 4; ++ks) {
        int kofs = ks * 32 + koff;
        bf16x8 afr[4], bfr[4];
        #pragma unroll
        for (int m = 0; m < 4; ++m) {
            int c = wr * 64 + m * 16 + frow;
            afr[m] = *(const bf16x8*)&Wvb[c * 128 + kofs];
        }
        #pragma unroll
        for (int n = 0; n < 4; ++n) {
            int i = wc * 64 + n * 16 + frow;
            bfr[n] = *(const bf16x8*)((const char*)Yt + (((i << 8) + (kofs << 1)) ^ ((i & 7) << 4)));
        }
        #pragma unroll
        for (int m = 0; m < 4; ++m)
            #pragma unroll
            for (int n = 0; n < 4; ++n)
                acc2[m][n] = __builtin_amdgcn_mfma_f32_16x16x32_bf16(afr[m], bfr[n], acc2[m][n], 0, 0, 0);
    }

    // ---- bias + write d_out ----
    float* ob = out + (size_t)b * CF * Tt + (size_t)f * Tt + (size_t)ib * 128;
    #pragma unroll
    for (int m = 0; m < 4; ++m) {
        #pragma unroll
        for (int r = 0; r < 4; ++r) {
            int c = wr * 64 + m * 16 + ((l >> 4) << 2) + r;
            float bvv = bv[c];
            #pragma unroll
            for (int n = 0; n < 4; ++n) {
                int col = wc * 64 + n * 16 + (l & 15);
                ob[(size_t)c * 64 * Tt + col] = acc2[m][n][r] + bvv;
            }
        }
    }
#undef STAGE
}

// ---------------------------------------------------------------------------
extern "C" void kernel_launch(void* const* d_in, const int* in_sizes, int n_in,
                              void* d_out, int out_size, void* d_ws, size_t ws_size,
                              hipStream_t stream) {
    const float* x       = (const float*)d_in[0];
    const float* Wq_conv = (const float*)d_in[1];
    const float* bq_conv = (const float*)d_in[2];
    const float* Wq_lin  = (const float*)d_in[3];
    const float* bq_lin  = (const float*)d_in[4];
    const float* Wk_conv = (const float*)d_in[5];
    const float* bk_conv = (const float*)d_in[6];
    const float* Wk_lin  = (const float*)d_in[7];
    const float* bk_lin  = (const float*)d_in[8];
    const float* Wv      = (const float*)d_in[9];
    const float* bv      = (const float*)d_in[10];
    float* out = (float*)d_out;

    float* ws   = (float*)d_ws;
    float* weff = ws;                         // 163840
    float* cqk  = weff + 163840;              // 32
    float* part = cqk + 32;                   // 5242880
    float* Qb   = part + 5242880;             // 81920
    float* Ktb  = Qb + 81920;                 // 81920
    float* Abf_f = Ktb + 81920;               // 8388608 floats = 16.7M bf16
    float* Xbf_f = Abf_f + 8388608;           // 33554432 floats = 67.1M bf16
    float* Wvb_f = Xbf_f + 33554432;          // 8192 floats = 16384 bf16
    ushort* Abf = (ushort*)Abf_f;
    ushort* Xbf = (ushort*)Xbf_f;
    ushort* Wvb = (ushort*)Wvb_f;

    k_prep <<<705, 256, 0, stream>>>(Wq_lin, Wq_conv, Wk_lin, Wk_conv,
                                     bq_conv, bq_lin, bk_conv, bk_lin, Wv,
                                     weff, cqk, Wvb);
    k_qk   <<<512, 256, 0, stream>>>(x, weff, part, Xbf);
    k_qkred<<<dim3(32, 20), 256, 0, stream>>>(part, cqk, Qb, Ktb);
    k_att  <<<8192, 256, 0, stream>>>(Qb, Ktb, Abf);
    k_pv_conv<<<dim3(64, 16, 4), 256, 0, stream>>>(Xbf, Abf, Wvb, bv, out);
}

// Round 8
// 437.126 us; speedup vs baseline: 10.1611x; 1.2070x over previous
//
#include <hip/hip_runtime.h>
#include <hip/hip_bf16.h>

#define Bq 4
#define Cc 128
#define Ff 64
#define Tt 2048
#define CF 8192     // C*F
#define NCHUNK 32   // cf chunks for QK pass
#define CHUNK 256   // cf per chunk

typedef __attribute__((ext_vector_type(4))) float f32x4;
typedef __attribute__((ext_vector_type(8))) short bf16x8;

__device__ inline ushort f2bf(float f) {
    __hip_bfloat16 h = __float2bfloat16(f);   // round-to-nearest
    return *reinterpret_cast<ushort*>(&h);
}

__device__ inline void gload_lds16(const void* g, void* l) {
    __builtin_amdgcn_global_load_lds(
        (const __attribute__((address_space(1))) void*)g,
        (__attribute__((address_space(3))) void*)l, 16, 0, 0);
}

// ---------------------------------------------------------------------------
// K1: merged prep.
// ---------------------------------------------------------------------------
__global__ void k_prep(const float* __restrict__ Wq_lin, const float* __restrict__ Wq_conv,
                       const float* __restrict__ Wk_lin, const float* __restrict__ Wk_conv,
                       const float* __restrict__ bq_conv, const float* __restrict__ bq_lin,
                       const float* __restrict__ bk_conv, const float* __restrict__ bk_lin,
                       const float* __restrict__ Wv,
                       float* __restrict__ weff, float* __restrict__ cqk,
                       ushort* __restrict__ Wvb) {
    int blk = blockIdx.x;
    if (blk < 640) {
        int gid = blk * 256 + threadIdx.x;
        if (gid >= CF * 20) return;
        int cf = gid / 20, d = gid % 20;
        int c = cf >> 6, f = cf & 63;
        float s = 0.f;
        if (d < 10) {
            #pragma unroll
            for (int o = 0; o < 4; ++o) s += Wq_lin[d * 256 + o * 64 + f] * Wq_conv[o * 128 + c];
        } else {
            int dd = d - 10;
            #pragma unroll
            for (int o = 0; o < 4; ++o) s += Wk_lin[dd * 256 + o * 64 + f] * Wk_conv[o * 128 + c];
        }
        weff[cf * 20 + d] = s;
    } else if (blk < 704) {
        int i = (blk - 640) * 256 + threadIdx.x;
        if (i < 16384) Wvb[i] = f2bf(Wv[i]);
    } else {
        int d = threadIdx.x;
        if (d >= 20) return;
        float s;
        if (d < 10) {
            s = bq_lin[d];
            for (int o = 0; o < 4; ++o) {
                float bb = bq_conv[o];
                for (int f = 0; f < 64; ++f) s += Wq_lin[d * 256 + o * 64 + f] * bb;
            }
        } else {
            int dd = d - 10;
            s = bk_lin[dd];
            for (int o = 0; o < 4; ++o) {
                float bb = bk_conv[o];
                for (int f = 0; f < 64; ++f) s += Wk_lin[dd * 256 + o * 64 + f] * bb;
            }
        }
        cqk[d] = s;
    }
}

// ---------------------------------------------------------------------------
// K2: QK partials + x->bf16 side-write.
// ---------------------------------------------------------------------------
__global__ __launch_bounds__(256) void k_qk(const float* __restrict__ x,
                                            const float* __restrict__ weff,
                                            float* __restrict__ partial,
                                            ushort* __restrict__ xbf) {
    int blk = blockIdx.x;
    int tt = blk & 3;
    int ch = (blk >> 2) & 31;
    int b  = blk >> 7;
    int t = tt * 512 + threadIdx.x * 2;
    const float* xb = x + (size_t)b * CF * Tt;
    ushort* xob = xbf + (size_t)b * CF * Tt;
    float acc[20][2];
    #pragma unroll
    for (int d = 0; d < 20; ++d) { acc[d][0] = 0.f; acc[d][1] = 0.f; }
    int cf0 = ch * CHUNK;
    for (int cf = cf0; cf < cf0 + CHUNK; ++cf) {
        float2 xv = *(const float2*)(xb + (size_t)cf * Tt + t);
        *(ushort2*)(xob + (size_t)cf * Tt + t) = make_ushort2(f2bf(xv.x), f2bf(xv.y));
        const float* w = weff + cf * 20;   // uniform address -> s_loads
        #pragma unroll
        for (int d = 0; d < 20; ++d) {
            float wv = w[d];
            acc[d][0] += wv * xv.x;
            acc[d][1] += wv * xv.y;
        }
    }
    float* pb = partial + (size_t)(b * NCHUNK + ch) * 20 * Tt;
    #pragma unroll
    for (int d = 0; d < 20; ++d)
        *(float2*)(pb + (size_t)d * Tt + t) = make_float2(acc[d][0], acc[d][1]);
}

// K3: reduce partials + const -> Q[b][t][10], Kt[b][10][t].  grid (32,20) x 256
__global__ void k_qkred(const float* __restrict__ partial, const float* __restrict__ cqk,
                        float* __restrict__ Q, float* __restrict__ Kt) {
    int t = blockIdx.x * 256 + threadIdx.x;  // 0..8191
    int d = blockIdx.y;                      // 0..19
    int b = t >> 11, tl = t & 2047;
    float s = cqk[d];
    #pragma unroll 4
    for (int ch = 0; ch < NCHUNK; ++ch)
        s += partial[((size_t)(b * NCHUNK + ch) * 20 + d) * Tt + tl];
    if (d < 10) Q[(size_t)(b * 2048 + tl) * 10 + d] = s;
    else        Kt[((size_t)b * 10 + (d - 10)) * Tt + tl] = s;
}

// ---------------------------------------------------------------------------
// K4: energy + softmax -> A_bf16[b][i][j].
// ---------------------------------------------------------------------------
__global__ __launch_bounds__(256) void k_att(const float* __restrict__ Q,
                                             const float* __restrict__ Kt,
                                             ushort* __restrict__ A) {
    int bi = blockIdx.x;
    int b = bi >> 11;
    __shared__ float qs[10];
    __shared__ float wmax[4];
    __shared__ float wsum[4];
    int tid = threadIdx.x;
    int lane = tid & 63, wid = tid >> 6;
    if (tid < 10) qs[tid] = Q[(size_t)bi * 10 + tid];
    __syncthreads();
    float q[10];
    #pragma unroll
    for (int d = 0; d < 10; ++d) q[d] = qs[d];
    const float* kb = Kt + (size_t)b * 10 * Tt;
    float e[8];
    #pragma unroll
    for (int jj = 0; jj < 8; ++jj) {
        int j = jj * 256 + tid;
        float s = 0.f;
        #pragma unroll
        for (int d = 0; d < 10; ++d) s += q[d] * kb[(size_t)d * Tt + j];
        e[jj] = s;
    }
    float m = e[0];
    #pragma unroll
    for (int jj = 1; jj < 8; ++jj) m = fmaxf(m, e[jj]);
    #pragma unroll
    for (int off = 32; off > 0; off >>= 1) m = fmaxf(m, __shfl_xor(m, off));
    if (lane == 0) wmax[wid] = m;
    __syncthreads();
    float M = fmaxf(fmaxf(wmax[0], wmax[1]), fmaxf(wmax[2], wmax[3]));
    float sum = 0.f;
    #pragma unroll
    for (int jj = 0; jj < 8; ++jj) { e[jj] = __expf(e[jj] - M); sum += e[jj]; }
    #pragma unroll
    for (int off = 32; off > 0; off >>= 1) sum += __shfl_xor(sum, off);
    if (lane == 0) wsum[wid] = sum;
    __syncthreads();
    float inv = 1.f / (wsum[0] + wsum[1] + wsum[2] + wsum[3]);
    ushort* arow = A + (size_t)bi * Tt;
    #pragma unroll
    for (int jj = 0; jj < 8; ++jj) arow[jj * 256 + tid] = f2bf(e[jj] * inv);
}

// ---------------------------------------------------------------------------
// K5: fused PV + channel conv — 256x256 counted-vmcnt schedule, RACE-FIXED:
// every counted vmcnt that gates reads of other waves' staged LDS is followed
// by s_barrier (per-wave wait + barrier => global visibility; m201 pattern).
// Per iter: ph0{readA0,B0; stgB0,B1; 16mfma} ph1{readB1; stgB2,B3; 16mfma}
//   vmcnt(4) BARRIER ph2{readA1; stgA0,A2; 16mfma} ph3{stgA1,A3; 16mfma}
//   vmcnt(2) BARRIER.
// Last iter peeled: vmcnt(0) up front, no stages -> full LDS free for Yt.
// grid (32 f-pairs, 8 i-tiles, 4 b) x 512
// ---------------------------------------------------------------------------
__global__ __launch_bounds__(512, 2) void k_pv_conv(const ushort* __restrict__ Xb,
                                                    const ushort* __restrict__ Ab,
                                                    const ushort* __restrict__ Wvb,
                                                    const float* __restrict__ bv,
                                                    float* __restrict__ out) {
    __shared__ float smemf[32768];           // 128 KB
    char* smem = (char*)smemf;
    int fb = blockIdx.x, ib = blockIdx.y, b = blockIdx.z;
    int f0 = fb * 2;
    int tid = threadIdx.x;
    int w = tid >> 6, l = tid & 63;
    int wm = w >> 2, wn = w & 3;             // stage-1 wave grid 2(M) x 4(N)
    int frow = l & 15, q = l >> 4, f7 = frow & 7;

    const ushort* xb0 = Xb + (size_t)b * CF * Tt + (size_t)f0 * Tt;
    const ushort* ab0 = Ab + (size_t)b * Tt * Tt + (size_t)ib * 256 * Tt;

    // staging source coords (pre-swizzled): row = g*64 + w*8 + (l>>3)
    int row_l = w * 8 + (l >> 3);
    int col_s = (((l & 7) ^ (l >> 3)) << 3);
    const ushort* srcB[4]; const ushort* srcA[4];
    #pragma unroll
    for (int g = 0; g < 4; ++g) {
        int row = g * 64 + row_l;
        srcB[g] = ab0 + (size_t)row * Tt + col_s;
        int n = (row & 127) * 64 + (row >> 7);   // n = c'*64 + (f - f0)
        srcA[g] = xb0 + (size_t)n * Tt + col_s;
    }

#define STG_B(g) gload_lds16(srcB[g] + k1, nb + (g) * 8192 + w * 1024)
#define STG_A(g) gload_lds16(srcA[g] + k1, nb + 32768 + (g) * 8192 + w * 1024)

    // fragment-read constants
    int swzk0 = (q ^ f7) << 4;
    int swzk1 = ((4 + q) ^ f7) << 4;
    int aBase = 32768 + (wm * 128 + frow) * 128;
    int bBase = (wn * 64 + frow) * 128;

#define READ_A(cb, MH)                                                          \
    _Pragma("unroll")                                                           \
    for (int mm = 0; mm < 4; ++mm) {                                            \
        afr[mm][0] = *(const bf16x8*)((cb) + aBase + (MH) * 8192 + mm * 2048 + swzk0); \
        afr[mm][1] = *(const bf16x8*)((cb) + aBase + (MH) * 8192 + mm * 2048 + swzk1); \
    }
#define READ_B(cb, NH, DST)                                                     \
    _Pragma("unroll")                                                           \
    for (int nn = 0; nn < 2; ++nn) {                                            \
        DST[nn][0] = *(const bf16x8*)((cb) + bBase + (NH) * 4096 + nn * 2048 + swzk0); \
        DST[nn][1] = *(const bf16x8*)((cb) + bBase + (NH) * 4096 + nn * 2048 + swzk1); \
    }
#define MFMA_Q(MH, NH, BFR)                                                     \
    __builtin_amdgcn_s_setprio(1);                                              \
    _Pragma("unroll")                                                           \
    for (int kk = 0; kk < 2; ++kk)                                              \
        _Pragma("unroll")                                                       \
        for (int mm = 0; mm < 4; ++mm)                                          \
            _Pragma("unroll")                                                   \
            for (int nn = 0; nn < 2; ++nn)                                      \
                acc[(MH) * 4 + mm][(NH) * 2 + nn] =                             \
                    __builtin_amdgcn_mfma_f32_16x16x32_bf16(                    \
                        afr[mm][kk], BFR[nn][kk],                               \
                        acc[(MH) * 4 + mm][(NH) * 2 + nn], 0, 0, 0);            \
    __builtin_amdgcn_s_setprio(0);

    f32x4 acc[8][4];
    #pragma unroll
    for (int m = 0; m < 8; ++m)
        #pragma unroll
        for (int n = 0; n < 4; ++n) acc[m][n] = (f32x4){0.f, 0.f, 0.f, 0.f};

    // prologue: stage buf0, queue order = steady state [B0..B3, A0,A2,A1,A3]
    {
        char* nb = smem;
        int k1 = 0;
        STG_B(0); STG_B(1); STG_B(2); STG_B(3);
        STG_A(0); STG_A(2); STG_A(1); STG_A(3);
    }
    asm volatile("s_waitcnt vmcnt(2)" ::: "memory");
    __builtin_amdgcn_s_barrier();   // -> B0..B3, A0, A2 of ALL waves visible

    #pragma unroll 1
    for (int t = 0; t < 32; ++t) {
        const char* cb = smem + (t & 1) * 65536;
        char* nb = smem + ((t + 1) & 1) * 65536;
        int k1 = (t + 1) * 64;
        bool st = (t < 31);
        if (!st) asm volatile("s_waitcnt vmcnt(0)" ::: "memory");
        bf16x8 afr[4][2], bfr0[2][2], bfr1[2][2];
        // ph0
        READ_A(cb, 0)
        READ_B(cb, 0, bfr0)
        if (st) { STG_B(0); STG_B(1); }
        MFMA_Q(0, 0, bfr0)
        // ph1
        READ_B(cb, 1, bfr1)
        if (st) { STG_B(2); STG_B(3); }
        MFMA_Q(0, 1, bfr1)
        // per-wave wait on own A1,A3 + barrier => ALL waves' A1,A3 visible
        asm volatile("s_waitcnt vmcnt(4)" ::: "memory");
        __builtin_amdgcn_s_barrier();
        // ph2
        READ_A(cb, 1)
        if (st) { STG_A(0); STG_A(2); }
        MFMA_Q(1, 1, bfr1)
        // ph3
        if (st) { STG_A(1); STG_A(3); }
        MFMA_Q(1, 0, bfr0)
        // per-wave wait on own B0'..B3',A0',A2' + barrier => global
        asm volatile("s_waitcnt vmcnt(2)" ::: "memory");
        __builtin_amdgcn_s_barrier();
    }

    // ---- transpose acc -> Yt[f=wm][i][c'] (bf16, swizzled), full-LDS overlay ----
    // acc[m][n][r] = Y[c'_loc = m*16 + q*4 + r][i = wn*64 + n*16 + frow]
    {
        char* Yt = smem + wm * 65536;
        #pragma unroll
        for (int n = 0; n < 4; ++n) {
            int i = wn * 64 + n * 16 + frow;
            int swz = (i & 7) << 4;
            #pragma unroll
            for (int m = 0; m < 8; ++m) {
                int cp = m * 16 + q * 4;
                ushort4 v;
                v.x = f2bf(acc[m][n][0]); v.y = f2bf(acc[m][n][1]);
                v.z = f2bf(acc[m][n][2]); v.w = f2bf(acc[m][n][3]);
                *(ushort4*)(Yt + ((i * 256 + cp * 2) ^ swz)) = v;
            }
        }
    }
    __syncthreads();

    // ---- stage 2: Out_f[c][i] = sum_c' Wvb[c][c'] * Yt[f][i][c'], K=128 ----
    int fh = w >> 2, wn2 = w & 3;
    const char* ytb = smem + fh * 65536;
    f32x4 acc2[8][4];
    #pragma unroll
    for (int m = 0; m < 8; ++m)
        #pragma unroll
        for (int n = 0; n < 4; ++n) acc2[m][n] = (f32x4){0.f, 0.f, 0.f, 0.f};
    #pragma unroll
    for (int ks = 0; ks < 4; ++ks) {
        int kofs = ks * 32 + q * 8;
        bf16x8 a2[8], b2[4];
        #pragma unroll
        for (int m = 0; m < 8; ++m)
            a2[m] = *(const bf16x8*)&Wvb[(m * 16 + frow) * 128 + kofs];
        #pragma unroll
        for (int n = 0; n < 4; ++n) {
            int i = wn2 * 64 + n * 16 + frow;
            b2[n] = *(const bf16x8*)(ytb + ((i * 256 + kofs * 2) ^ ((i & 7) << 4)));
        }
        #pragma unroll
        for (int m = 0; m < 8; ++m)
            #pragma unroll
            for (int n = 0; n < 4; ++n)
                acc2[m][n] = __builtin_amdgcn_mfma_f32_16x16x32_bf16(a2[m], b2[n], acc2[m][n], 0, 0, 0);
    }

    // ---- bias + write d_out ----
    float* ob = out + (size_t)b * CF * Tt + (size_t)(f0 + fh) * Tt
                    + (size_t)ib * 256 + wn2 * 64;
    #pragma unroll
    for (int m = 0; m < 8; ++m) {
        #pragma unroll
        for (int r = 0; r < 4; ++r) {
            int c = m * 16 + q * 4 + r;
            float bvv = bv[c];
            #pragma unroll
            for (int n = 0; n < 4; ++n)
                ob[(size_t)c * 64 * Tt + n * 16 + frow] = acc2[m][n][r] + bvv;
        }
    }
#undef STG_A
#undef STG_B
#undef READ_A
#undef READ_B
#undef MFMA_Q
}

// ---------------------------------------------------------------------------
extern "C" void kernel_launch(void* const* d_in, const int* in_sizes, int n_in,
                              void* d_out, int out_size, void* d_ws, size_t ws_size,
                              hipStream_t stream) {
    const float* x       = (const float*)d_in[0];
    const float* Wq_conv = (const float*)d_in[1];
    const float* bq_conv = (const float*)d_in[2];
    const float* Wq_lin  = (const float*)d_in[3];
    const float* bq_lin  = (const float*)d_in[4];
    const float* Wk_conv = (const float*)d_in[5];
    const float* bk_conv = (const float*)d_in[6];
    const float* Wk_lin  = (const float*)d_in[7];
    const float* bk_lin  = (const float*)d_in[8];
    const float* Wv      = (const float*)d_in[9];
    const float* bv      = (const float*)d_in[10];
    float* out = (float*)d_out;

    float* ws   = (float*)d_ws;
    float* weff = ws;                         // 163840
    float* cqk  = weff + 163840;              // 32
    float* part = cqk + 32;                   // 5242880
    float* Qb   = part + 5242880;             // 81920
    float* Ktb  = Qb + 81920;                 // 81920
    float* Abf_f = Ktb + 81920;               // 8388608 floats = 16.7M bf16
    float* Xbf_f = Abf_f + 8388608;           // 33554432 floats = 67.1M bf16
    float* Wvb_f = Xbf_f + 33554432;          // 8192 floats = 16384 bf16
    ushort* Abf = (ushort*)Abf_f;
    ushort* Xbf = (ushort*)Xbf_f;
    ushort* Wvb = (ushort*)Wvb_f;

    k_prep <<<705, 256, 0, stream>>>(Wq_lin, Wq_conv, Wk_lin, Wk_conv,
                                     bq_conv, bq_lin, bk_conv, bk_lin, Wv,
                                     weff, cqk, Wvb);
    k_qk   <<<512, 256, 0, stream>>>(x, weff, part, Xbf);
    k_qkred<<<dim3(32, 20), 256, 0, stream>>>(part, cqk, Qb, Ktb);
    k_att  <<<8192, 256, 0, stream>>>(Qb, Ktb, Abf);
    k_pv_conv<<<dim3(32, 8, 4), 512, 0, stream>>>(Xbf, Abf, Wvb, bv, out);
}